// Round 1
// baseline (9746.638 us; speedup 1.0000x reference)
//
#include <hip/hip_runtime.h>
#include <math.h>

#define TPB 256

// ---------------- Gauss-Jordan inverse (one block; N in {32,64,128}) -------
__global__ void gj_inverse_kernel(const float* __restrict__ A,
                                  float* __restrict__ Ainv, int N) {
    __shared__ float sA[128 * 128];
    int tid = threadIdx.x;
    for (int idx = tid; idx < N * N; idx += TPB) sA[idx] = A[idx];
    __syncthreads();
    int tpr  = TPB / N;          // threads per row
    int i    = tid / tpr;        // my row
    int span = N / tpr;          // cols per thread
    int j0   = (tid % tpr) * span;
    for (int k = 0; k < N; ++k) {
        float colv = sA[i * N + k];   // pivot (row k) or elimination factor
        __syncthreads();
        if (i == k) {
            float pi = 1.0f / colv;
            for (int j = j0; j < j0 + span; ++j)
                sA[k * N + j] = (j == k) ? pi : sA[k * N + j] * pi;
        }
        __syncthreads();
        if (i != k) {
            for (int j = j0; j < j0 + span; ++j) {
                float v = ((j == k) ? 0.0f : sA[i * N + j]) - sA[k * N + j] * colv;
                sA[i * N + j] = v;
            }
        }
        __syncthreads();
    }
    for (int idx = tid; idx < N * N; idx += TPB) Ainv[idx] = sA[idx];
}

// ---------------- small transpose 128x128 ----------------------------------
__global__ void transpose128_kernel(const float* __restrict__ in,
                                    float* __restrict__ out) {
    int idx = blockIdx.x * TPB + threadIdx.x;  // 16384 total
    int r = idx >> 7, c = idx & 127;
    out[c * 128 + r] = in[idx];
}

// ---------------- build P^T and Pinv from kron factors ---------------------
// P[i,j] = diag[i] * L[i>>6, j>>6] * R[i&63, j&63];  PT[j,i] = P[i,j]
__global__ void build_PT_kernel(const float* __restrict__ L,
                                const float* __restrict__ R,
                                const float* __restrict__ dg,
                                float* __restrict__ PT) {
    int idx = blockIdx.x * TPB + threadIdx.x;   // 4M total
    int j = idx >> 11;      // PT row
    int i = idx & 2047;     // PT col
    PT[idx] = dg[i] * L[(i >> 6) * 32 + (j >> 6)] * R[((i & 63) << 6) + (j & 63)];
}
// Pinv[i,j] = invL[i>>6, j>>6] * invR[i&63, j&63] / diag[j]
__global__ void build_Pinv_kernel(const float* __restrict__ invL,
                                  const float* __restrict__ invR,
                                  const float* __restrict__ dg,
                                  float* __restrict__ Pinv) {
    int idx = blockIdx.x * TPB + threadIdx.x;
    int i = idx >> 11;
    int j = idx & 2047;
    Pinv[idx] = invL[(i >> 6) * 32 + (j >> 6)] * invR[((i & 63) << 6) + (j & 63)] / dg[j];
}

// ---------------- generic tiled fp32 GEMM ----------------------------------
// C[m,n] = alpha * sum_k A[m,k] * (TRANS_B ? B[n,k] : B[k,n])
// Requires M,N multiples of 64 and K multiple of 16.
template <bool TRANS_B>
__global__ __launch_bounds__(256) void gemm_kernel(
    const float* __restrict__ A, const float* __restrict__ B,
    float* __restrict__ C, int K, int lda, int ldb, int ldc, float alpha) {
    __shared__ float As[16][68];
    __shared__ float Bs[16][68];
    int tid = threadIdx.x;
    int m0 = blockIdx.y * 64, n0 = blockIdx.x * 64;
    int tx = tid & 15, ty = tid >> 4;
    float acc[4][4] = {};
    for (int k0 = 0; k0 < K; k0 += 16) {
#pragma unroll
        for (int it = 0; it < 4; ++it) {
            int idx = tid + it * 256;
            int m = idx >> 4, kk = idx & 15;
            As[kk][m] = A[(size_t)(m0 + m) * lda + k0 + kk];
        }
#pragma unroll
        for (int it = 0; it < 4; ++it) {
            int idx = tid + it * 256;
            if (TRANS_B) {
                int n = idx >> 4, kk = idx & 15;
                Bs[kk][n] = B[(size_t)(n0 + n) * ldb + k0 + kk];
            } else {
                int kk = idx >> 6, n = idx & 63;
                Bs[kk][n] = B[(size_t)(k0 + kk) * ldb + n0 + n];
            }
        }
        __syncthreads();
#pragma unroll
        for (int kk = 0; kk < 16; ++kk) {
            float a[4], b[4];
#pragma unroll
            for (int i = 0; i < 4; ++i) a[i] = As[kk][ty * 4 + i];
#pragma unroll
            for (int j = 0; j < 4; ++j) b[j] = Bs[kk][tx * 4 + j];
#pragma unroll
            for (int i = 0; i < 4; ++i)
#pragma unroll
                for (int j = 0; j < 4; ++j) acc[i][j] += a[i] * b[j];
        }
        __syncthreads();
    }
#pragma unroll
    for (int i = 0; i < 4; ++i)
#pragma unroll
        for (int j = 0; j < 4; ++j)
            C[(size_t)(m0 + ty * 4 + i) * ldc + n0 + tx * 4 + j] = alpha * acc[i][j];
}

// ---------------- per-row fake_quant ---------------------------------------
// s = max(absmax/127, 1e-8); out = clip(rint(x/s), -127, 127)*s
__global__ void rowquant_kernel(const float* __restrict__ in,
                                float* __restrict__ out, int cols) {
    __shared__ float red[TPB];
    int row = blockIdx.x, tid = threadIdx.x;
    const float* x = in + (size_t)row * cols;
    float* y = out + (size_t)row * cols;
    float m = 0.0f;
    for (int j = tid; j < cols; j += TPB) m = fmaxf(m, fabsf(x[j]));
    red[tid] = m;
    __syncthreads();
    for (int s = 128; s > 0; s >>= 1) {
        if (tid < s) red[tid] = fmaxf(red[tid], red[tid + s]);
        __syncthreads();
    }
    float scale = fmaxf(red[0] / 127.0f, 1e-8f);
    for (int j = tid; j < cols; j += TPB) {
        float q = rintf(x[j] / scale);
        q = fminf(fmaxf(q, -127.0f), 127.0f);
        y[j] = q * scale;
    }
}

// ---------------- RoPE (in place), x:(S, nh, 128), cos/sin:(S,128) ---------
__global__ void rope_kernel(float* __restrict__ x, const float* __restrict__ c,
                            const float* __restrict__ s, int nh) {
    int idx = blockIdx.x * TPB + threadIdx.x;  // S*nh*64 total
    int d = idx & 63;
    int t = idx >> 6;
    int h = t % nh;
    int sq = t / nh;
    size_t base = ((size_t)sq * nh + h) * 128;
    float a = x[base + d], b = x[base + d + 64];
    float c1 = c[sq * 128 + d], s1 = s[sq * 128 + d];
    float c2 = c[sq * 128 + d + 64], s2 = s[sq * 128 + d + 64];
    x[base + d]      = a * c1 - b * s1;
    x[base + d + 64] = b * c2 + a * s2;
}

// ---------------- causal softmax, in place, scores: S x S ------------------
__global__ void softmax_causal_kernel(float* __restrict__ scores, int S) {
    __shared__ float red[TPB];
    int qi = blockIdx.x, tid = threadIdx.x;
    float* row = scores + (size_t)qi * S;
    int valid = qi + 1;
    float m = -3.0e38f;
    for (int j = tid; j < valid; j += TPB) m = fmaxf(m, row[j]);
    red[tid] = m;
    __syncthreads();
    for (int s = 128; s > 0; s >>= 1) {
        if (tid < s) red[tid] = fmaxf(red[tid], red[tid + s]);
        __syncthreads();
    }
    float rmax = red[0];
    __syncthreads();
    float sum = 0.0f;
    for (int j = tid; j < valid; j += TPB) {
        float e = expf(row[j] - rmax);
        row[j] = e;
        sum += e;
    }
    red[tid] = sum;
    __syncthreads();
    for (int s = 128; s > 0; s >>= 1) {
        if (tid < s) red[tid] += red[tid + s];
        __syncthreads();
    }
    float inv = 1.0f / red[0];
    for (int j = tid; j < valid; j += TPB) row[j] *= inv;
    for (int j = valid + tid; j < S; j += TPB) row[j] = 0.0f;
}

// ===========================================================================
extern "C" void kernel_launch(void* const* d_in, const int* in_sizes, int n_in,
                              void* d_out, int out_size, void* d_ws, size_t ws_size,
                              hipStream_t stream) {
    const int S = 2048, D = 2048, H = 16, KVH = 8, HD = 128;
    const float* hidden = (const float*)d_in[0];
    const float* cosp   = (const float*)d_in[1];
    const float* sinp   = (const float*)d_in[2];
    const float* Wq     = (const float*)d_in[3];
    const float* Wk     = (const float*)d_in[4];
    const float* Wv     = (const float*)d_in[5];
    const float* Wo     = (const float*)d_in[6];
    const float* Lp     = (const float*)d_in[7];
    const float* Rp     = (const float*)d_in[8];
    const float* diag   = (const float*)d_in[9];
    const float* Tkp    = (const float*)d_in[10];
    const float* Tvp    = (const float*)d_in[11];
    float* out = (float*)d_out;

    float* ws = (float*)d_ws;
    const size_t F4M = 4194304, F2M = 2097152;
    float* PT   = ws;                       // 4M  -> later: scores
    float* PINV = ws + F4M;                 // 4M  -> later: q2
    float* X    = ws + 2 * F4M;             // 4M  -> later: o2
    float* WQ   = ws + 3 * F4M;             // 4M  -> later: o
    float* WK   = ws + 4 * F4M;             // 2M  -> later: k2
    float* WVP  = ws + 4 * F4M + F2M;       // 2M  -> later: v
    float* WV   = ws + 4 * F4M + 2 * F2M;   // 2M
    float* Q    = ws + 4 * F4M + 3 * F2M;   // 4M  -> later: Wo_q
    float* KB   = ws + 5 * F4M + 3 * F2M;   // 2M
    float* SMALL= ws + 5 * F4M + 4 * F2M;
    float* invL  = SMALL;            // 1024
    float* invR  = SMALL + 1024;     // 4096
    float* invTk = SMALL + 5120;     // 16384
    float* invTv = SMALL + 21504;    // 16384
    float* TvT   = SMALL + 37888;    // 16384

    float* scores = PT;
    float* q2 = PINV;
    float* o2 = X;
    float* o  = WQ;
    float* k2 = WK;
    float* v  = WVP;
    float* WoQ = Q;

    auto gemm = [&](bool transB, const float* A, const float* B, float* C,
                    int M, int N, int K, int lda, int ldb, int ldc, float alpha) {
        dim3 grid(N / 64, M / 64), block(256);
        if (transB)
            gemm_kernel<true><<<grid, block, 0, stream>>>(A, B, C, K, lda, ldb, ldc, alpha);
        else
            gemm_kernel<false><<<grid, block, 0, stream>>>(A, B, C, K, lda, ldb, ldc, alpha);
    };

    // ---- small inverses & transposes ----
    gj_inverse_kernel<<<1, TPB, 0, stream>>>(Lp, invL, 32);
    gj_inverse_kernel<<<1, TPB, 0, stream>>>(Rp, invR, 64);
    gj_inverse_kernel<<<1, TPB, 0, stream>>>(Tkp, invTk, 128);
    gj_inverse_kernel<<<1, TPB, 0, stream>>>(Tvp, invTv, 128);
    transpose128_kernel<<<64, TPB, 0, stream>>>(Tvp, TvT);
    build_PT_kernel<<<16384, TPB, 0, stream>>>(Lp, Rp, diag, PT);
    build_Pinv_kernel<<<16384, TPB, 0, stream>>>(invL, invR, diag, PINV);

    // ---- weight prep: W_eff = fake_quant(W @ Pinv^T) ----
    gemm(true, Wq, PINV, WQ, 2048, 2048, 2048, 2048, 2048, 2048, 1.0f);
    rowquant_kernel<<<2048, TPB, 0, stream>>>(WQ, WQ, 2048);
    gemm(true, Wk, PINV, WK, 1024, 2048, 2048, 2048, 2048, 2048, 1.0f);
    rowquant_kernel<<<1024, TPB, 0, stream>>>(WK, WK, 2048);
    gemm(true, Wv, PINV, WVP, 1024, 2048, 2048, 2048, 2048, 2048, 1.0f);
    for (int kv = 0; kv < KVH; ++kv)  // Wv_eff[k] = Tv^T @ WvP[k]
        gemm(false, TvT, WVP + (size_t)kv * 128 * 2048, WV + (size_t)kv * 128 * 2048,
             128, 2048, 128, 128, 2048, 2048, 1.0f);
    rowquant_kernel<<<1024, TPB, 0, stream>>>(WV, WV, 2048);

    // ---- x = fake_quant(hidden @ P) ----
    gemm(true, hidden, PT, X, 2048, 2048, 2048, 2048, 2048, 2048, 1.0f);
    rowquant_kernel<<<2048, TPB, 0, stream>>>(X, X, 2048);

    // ---- q, k, v projections ----
    gemm(true, X, WQ, Q, 2048, 2048, 2048, 2048, 2048, 2048, 1.0f);
    gemm(true, X, WK, KB, 2048, 1024, 2048, 2048, 2048, 1024, 1.0f);
    gemm(true, X, WV, v, 2048, 1024, 2048, 2048, 2048, 1024, 1.0f);

    // ---- RoPE ----
    rope_kernel<<<(S * H * 64) / TPB, TPB, 0, stream>>>(Q, cosp, sinp, H);
    rope_kernel<<<(S * KVH * 64) / TPB, TPB, 0, stream>>>(KB, cosp, sinp, KVH);

    // ---- q2 = q @ inv(Tk)^T ; k2 = fake_quant(k @ Tk) ; v = fake_quant(v) --
    for (int h = 0; h < H; ++h)
        gemm(true, Q + h * 128, invTk, q2 + h * 128, 2048, 128, 128, 2048, 128, 2048, 1.0f);
    for (int g = 0; g < KVH; ++g)
        gemm(false, KB + g * 128, Tkp, k2 + g * 128, 2048, 128, 128, 1024, 128, 1024, 1.0f);
    rowquant_kernel<<<S * KVH, TPB, 0, stream>>>(k2, k2, 128);
    rowquant_kernel<<<S * KVH, TPB, 0, stream>>>(v, v, 128);

    // ---- attention per head (scores buffer reused) ----
    const float scale = 0.08838834764831845f;  // 128^-0.5
    for (int h = 0; h < H; ++h) {
        int g = h >> 1;
        gemm(true, q2 + h * 128, k2 + g * 128, scores, 2048, 2048, 128,
             2048, 1024, 2048, scale);
        softmax_causal_kernel<<<S, TPB, 0, stream>>>(scores, S);
        gemm(false, scores, v + g * 128, o + h * 128, 2048, 128, 2048,
             2048, 1024, 2048, 1.0f);
    }

    // ---- o2 = o @ inv(Tv); out = fake_quant(o2) @ fake_quant(Wo)^T --------
    for (int h = 0; h < H; ++h)
        gemm(false, o + h * 128, invTv, o2 + h * 128, 2048, 128, 128, 2048, 128, 2048, 1.0f);
    rowquant_kernel<<<2048, TPB, 0, stream>>>(o2, o2, 2048);
    rowquant_kernel<<<2048, TPB, 0, stream>>>(Wo, WoQ, 2048);
    gemm(true, o2, WoQ, out, 2048, 2048, 2048, 2048, 2048, 2048, 1.0f);

    (void)in_sizes; (void)n_in; (void)out_size; (void)ws_size;
}

// Round 2
// 4713.453 us; speedup vs baseline: 2.0678x; 2.0678x over previous
//
#include <hip/hip_runtime.h>
#include <math.h>

#define TPB 256
#define INV_TPB 1024

// ---------------- parallel Gauss-Jordan inverse, 4 matrices in one launch --
// block b inverts matrix b. N in {32,64,128} (power of two).
__global__ __launch_bounds__(INV_TPB) void gj_inverse4_kernel(
    const float* __restrict__ A0, float* __restrict__ I0,
    const float* __restrict__ A1, float* __restrict__ I1,
    const float* __restrict__ A2, float* __restrict__ I2,
    const float* __restrict__ A3, float* __restrict__ I3) {
    __shared__ float sA[128 * 128];
    __shared__ float rowbuf[128];
    __shared__ float colbuf[128];
    const float* A;
    float* Ainv;
    int N;
    switch (blockIdx.x) {
        case 0:  A = A0; Ainv = I0; N = 32;  break;
        case 1:  A = A1; Ainv = I1; N = 64;  break;
        case 2:  A = A2; Ainv = I2; N = 128; break;
        default: A = A3; Ainv = I3; N = 128; break;
    }
    const int lg = (N == 32) ? 5 : (N == 64) ? 6 : 7;
    const int NN = N * N;
    int tid = threadIdx.x;
    for (int idx = tid; idx < NN; idx += INV_TPB) sA[idx] = A[idx];
    __syncthreads();
    for (int k = 0; k < N; ++k) {
        if (tid < N) {
            float p = sA[(k << lg) + k];
            rowbuf[tid] = (tid == k) ? (1.0f / p) : sA[(k << lg) + tid] / p;
            colbuf[tid] = sA[(tid << lg) + k];
        }
        __syncthreads();
        for (int idx = tid; idx < NN; idx += INV_TPB) {
            int i = idx >> lg, j = idx & (N - 1);
            float v;
            if (i == k) v = rowbuf[j];
            else        v = ((j == k) ? 0.0f : sA[idx]) - colbuf[i] * rowbuf[j];
            sA[idx] = v;
        }
        __syncthreads();
    }
    for (int idx = tid; idx < NN; idx += INV_TPB) Ainv[idx] = sA[idx];
}

// ---------------- small transpose 128x128 ----------------------------------
__global__ void transpose128_kernel(const float* __restrict__ in,
                                    float* __restrict__ out) {
    int idx = blockIdx.x * TPB + threadIdx.x;  // 16384 total
    int r = idx >> 7, c = idx & 127;
    out[c * 128 + r] = in[idx];
}

// ---------------- build P^T and Pinv from kron factors ---------------------
// P[i,j] = diag[i] * L[i>>6, j>>6] * R[i&63, j&63];  PT[j,i] = P[i,j]
__global__ void build_PT_kernel(const float* __restrict__ L,
                                const float* __restrict__ R,
                                const float* __restrict__ dg,
                                float* __restrict__ PT) {
    int idx = blockIdx.x * TPB + threadIdx.x;   // 4M total
    int j = idx >> 11;      // PT row
    int i = idx & 2047;     // PT col
    PT[idx] = dg[i] * L[(i >> 6) * 32 + (j >> 6)] * R[((i & 63) << 6) + (j & 63)];
}
// Pinv[i,j] = invL[i>>6, j>>6] * invR[i&63, j&63] / diag[j]
__global__ void build_Pinv_kernel(const float* __restrict__ invL,
                                  const float* __restrict__ invR,
                                  const float* __restrict__ dg,
                                  float* __restrict__ Pinv) {
    int idx = blockIdx.x * TPB + threadIdx.x;
    int i = idx >> 11;
    int j = idx & 2047;
    Pinv[idx] = invL[(i >> 6) * 32 + (j >> 6)] * invR[((i & 63) << 6) + (j & 63)] / dg[j];
}

// ---------------- generic tiled fp32 GEMM ----------------------------------
// C[m,n] = alpha * sum_k A[m,k] * (TRANS_B ? B[n,k] : B[k,n])
// Requires M,N multiples of 64 and K multiple of 16.
template <bool TRANS_B>
__global__ __launch_bounds__(256) void gemm_kernel(
    const float* __restrict__ A, const float* __restrict__ B,
    float* __restrict__ C, int K, int lda, int ldb, int ldc, float alpha) {
    __shared__ float As[16][68];
    __shared__ float Bs[16][68];
    int tid = threadIdx.x;
    int m0 = blockIdx.y * 64, n0 = blockIdx.x * 64;
    int tx = tid & 15, ty = tid >> 4;
    float acc[4][4] = {};
    for (int k0 = 0; k0 < K; k0 += 16) {
#pragma unroll
        for (int it = 0; it < 4; ++it) {
            int idx = tid + it * 256;
            int m = idx >> 4, kk = idx & 15;
            As[kk][m] = A[(size_t)(m0 + m) * lda + k0 + kk];
        }
#pragma unroll
        for (int it = 0; it < 4; ++it) {
            int idx = tid + it * 256;
            if (TRANS_B) {
                int n = idx >> 4, kk = idx & 15;
                Bs[kk][n] = B[(size_t)(n0 + n) * ldb + k0 + kk];
            } else {
                int kk = idx >> 6, n = idx & 63;
                Bs[kk][n] = B[(size_t)(k0 + kk) * ldb + n0 + n];
            }
        }
        __syncthreads();
#pragma unroll
        for (int kk = 0; kk < 16; ++kk) {
            float a[4], b[4];
#pragma unroll
            for (int i = 0; i < 4; ++i) a[i] = As[kk][ty * 4 + i];
#pragma unroll
            for (int j = 0; j < 4; ++j) b[j] = Bs[kk][tx * 4 + j];
#pragma unroll
            for (int i = 0; i < 4; ++i)
#pragma unroll
                for (int j = 0; j < 4; ++j) acc[i][j] += a[i] * b[j];
        }
        __syncthreads();
    }
#pragma unroll
    for (int i = 0; i < 4; ++i)
#pragma unroll
        for (int j = 0; j < 4; ++j)
            C[(size_t)(m0 + ty * 4 + i) * ldc + n0 + tx * 4 + j] = alpha * acc[i][j];
}

// ---------------- per-row fake_quant ---------------------------------------
// s = max(absmax/127, 1e-8); out = clip(rint(x/s), -127, 127)*s
__global__ void rowquant_kernel(const float* __restrict__ in,
                                float* __restrict__ out, int cols) {
    __shared__ float red[TPB];
    int row = blockIdx.x, tid = threadIdx.x;
    const float* x = in + (size_t)row * cols;
    float* y = out + (size_t)row * cols;
    float m = 0.0f;
    for (int j = tid; j < cols; j += TPB) m = fmaxf(m, fabsf(x[j]));
    red[tid] = m;
    __syncthreads();
    for (int s = 128; s > 0; s >>= 1) {
        if (tid < s) red[tid] = fmaxf(red[tid], red[tid + s]);
        __syncthreads();
    }
    float scale = fmaxf(red[0] / 127.0f, 1e-8f);
    for (int j = tid; j < cols; j += TPB) {
        float q = rintf(x[j] / scale);
        q = fminf(fmaxf(q, -127.0f), 127.0f);
        y[j] = q * scale;
    }
}

// ---------------- RoPE (in place), x:(S, nh, 128), cos/sin:(S,128) ---------
__global__ void rope_kernel(float* __restrict__ x, const float* __restrict__ c,
                            const float* __restrict__ s, int nh) {
    int idx = blockIdx.x * TPB + threadIdx.x;  // S*nh*64 total
    int d = idx & 63;
    int t = idx >> 6;
    int h = t % nh;
    int sq = t / nh;
    size_t base = ((size_t)sq * nh + h) * 128;
    float a = x[base + d], b = x[base + d + 64];
    float c1 = c[sq * 128 + d], s1 = s[sq * 128 + d];
    float c2 = c[sq * 128 + d + 64], s2 = s[sq * 128 + d + 64];
    x[base + d]      = a * c1 - b * s1;
    x[base + d + 64] = b * c2 + a * s2;
}

// ---------------- causal softmax, in place, scores: S x S ------------------
__global__ void softmax_causal_kernel(float* __restrict__ scores, int S) {
    __shared__ float red[TPB];
    int qi = blockIdx.x, tid = threadIdx.x;
    float* row = scores + (size_t)qi * S;
    int valid = qi + 1;
    float m = -3.0e38f;
    for (int j = tid; j < valid; j += TPB) m = fmaxf(m, row[j]);
    red[tid] = m;
    __syncthreads();
    for (int s = 128; s > 0; s >>= 1) {
        if (tid < s) red[tid] = fmaxf(red[tid], red[tid + s]);
        __syncthreads();
    }
    float rmax = red[0];
    __syncthreads();
    float sum = 0.0f;
    for (int j = tid; j < valid; j += TPB) {
        float e = expf(row[j] - rmax);
        row[j] = e;
        sum += e;
    }
    red[tid] = sum;
    __syncthreads();
    for (int s = 128; s > 0; s >>= 1) {
        if (tid < s) red[tid] += red[tid + s];
        __syncthreads();
    }
    float inv = 1.0f / red[0];
    for (int j = tid; j < valid; j += TPB) row[j] *= inv;
    for (int j = valid + tid; j < S; j += TPB) row[j] = 0.0f;
}

// ===========================================================================
extern "C" void kernel_launch(void* const* d_in, const int* in_sizes, int n_in,
                              void* d_out, int out_size, void* d_ws, size_t ws_size,
                              hipStream_t stream) {
    const int S = 2048, H = 16, KVH = 8;
    const float* hidden = (const float*)d_in[0];
    const float* cosp   = (const float*)d_in[1];
    const float* sinp   = (const float*)d_in[2];
    const float* Wq     = (const float*)d_in[3];
    const float* Wk     = (const float*)d_in[4];
    const float* Wv     = (const float*)d_in[5];
    const float* Wo     = (const float*)d_in[6];
    const float* Lp     = (const float*)d_in[7];
    const float* Rp     = (const float*)d_in[8];
    const float* diag   = (const float*)d_in[9];
    const float* Tkp    = (const float*)d_in[10];
    const float* Tvp    = (const float*)d_in[11];
    float* out = (float*)d_out;

    float* ws = (float*)d_ws;
    const size_t F4M = 4194304, F2M = 2097152;
    float* PT   = ws;                       // 4M  -> later: scores
    float* PINV = ws + F4M;                 // 4M  -> later: q2
    float* X    = ws + 2 * F4M;             // 4M  -> later: o2
    float* WQ   = ws + 3 * F4M;             // 4M  -> later: o
    float* WK   = ws + 4 * F4M;             // 2M  -> later: k2
    float* WVP  = ws + 4 * F4M + F2M;       // 2M  -> later: v
    float* WV   = ws + 4 * F4M + 2 * F2M;   // 2M
    float* Q    = ws + 4 * F4M + 3 * F2M;   // 4M  -> later: Wo_q
    float* KB   = ws + 5 * F4M + 3 * F2M;   // 2M
    float* SMALL= ws + 5 * F4M + 4 * F2M;
    float* invL  = SMALL;            // 1024
    float* invR  = SMALL + 1024;     // 4096
    float* invTk = SMALL + 5120;     // 16384
    float* invTv = SMALL + 21504;    // 16384
    float* TvT   = SMALL + 37888;    // 16384

    float* scores = PT;
    float* q2 = PINV;
    float* o2 = X;
    float* o  = WQ;
    float* k2 = WK;
    float* v  = WVP;
    float* WoQ = Q;

    auto gemm = [&](bool transB, const float* A, const float* B, float* C,
                    int M, int N, int K, int lda, int ldb, int ldc, float alpha) {
        dim3 grid(N / 64, M / 64), block(256);
        if (transB)
            gemm_kernel<true><<<grid, block, 0, stream>>>(A, B, C, K, lda, ldb, ldc, alpha);
        else
            gemm_kernel<false><<<grid, block, 0, stream>>>(A, B, C, K, lda, ldb, ldc, alpha);
    };

    // ---- small inverses (one launch, 4 concurrent blocks) & transposes ----
    gj_inverse4_kernel<<<4, INV_TPB, 0, stream>>>(Lp, invL, Rp, invR,
                                                  Tkp, invTk, Tvp, invTv);
    transpose128_kernel<<<64, TPB, 0, stream>>>(Tvp, TvT);
    build_PT_kernel<<<16384, TPB, 0, stream>>>(Lp, Rp, diag, PT);
    build_Pinv_kernel<<<16384, TPB, 0, stream>>>(invL, invR, diag, PINV);

    // ---- weight prep: W_eff = fake_quant(W @ Pinv^T) ----
    gemm(true, Wq, PINV, WQ, 2048, 2048, 2048, 2048, 2048, 2048, 1.0f);
    rowquant_kernel<<<2048, TPB, 0, stream>>>(WQ, WQ, 2048);
    gemm(true, Wk, PINV, WK, 1024, 2048, 2048, 2048, 2048, 2048, 1.0f);
    rowquant_kernel<<<1024, TPB, 0, stream>>>(WK, WK, 2048);
    gemm(true, Wv, PINV, WVP, 1024, 2048, 2048, 2048, 2048, 2048, 1.0f);
    for (int kv = 0; kv < KVH; ++kv)  // Wv_eff[k] = Tv^T @ WvP[k]
        gemm(false, TvT, WVP + (size_t)kv * 128 * 2048, WV + (size_t)kv * 128 * 2048,
             128, 2048, 128, 128, 2048, 2048, 1.0f);
    rowquant_kernel<<<1024, TPB, 0, stream>>>(WV, WV, 2048);

    // ---- x = fake_quant(hidden @ P) ----
    gemm(true, hidden, PT, X, 2048, 2048, 2048, 2048, 2048, 2048, 1.0f);
    rowquant_kernel<<<2048, TPB, 0, stream>>>(X, X, 2048);

    // ---- q, k, v projections ----
    gemm(true, X, WQ, Q, 2048, 2048, 2048, 2048, 2048, 2048, 1.0f);
    gemm(true, X, WK, KB, 2048, 1024, 2048, 2048, 2048, 1024, 1.0f);
    gemm(true, X, WV, v, 2048, 1024, 2048, 2048, 2048, 1024, 1.0f);

    // ---- RoPE ----
    rope_kernel<<<(S * H * 64) / TPB, TPB, 0, stream>>>(Q, cosp, sinp, H);
    rope_kernel<<<(S * KVH * 64) / TPB, TPB, 0, stream>>>(KB, cosp, sinp, KVH);

    // ---- q2 = q @ inv(Tk)^T ; k2 = fake_quant(k @ Tk) ; v = fake_quant(v) --
    for (int h = 0; h < H; ++h)
        gemm(true, Q + h * 128, invTk, q2 + h * 128, 2048, 128, 128, 2048, 128, 2048, 1.0f);
    for (int g = 0; g < KVH; ++g)
        gemm(false, KB + g * 128, Tkp, k2 + g * 128, 2048, 128, 128, 1024, 128, 1024, 1.0f);
    rowquant_kernel<<<S * KVH, TPB, 0, stream>>>(k2, k2, 128);
    rowquant_kernel<<<S * KVH, TPB, 0, stream>>>(v, v, 128);

    // ---- attention per head (scores buffer reused) ----
    const float scale = 0.08838834764831845f;  // 128^-0.5
    for (int h = 0; h < H; ++h) {
        int g = h >> 1;
        gemm(true, q2 + h * 128, k2 + g * 128, scores, 2048, 2048, 128,
             2048, 1024, 2048, scale);
        softmax_causal_kernel<<<S, TPB, 0, stream>>>(scores, S);
        gemm(false, scores, v + g * 128, o + h * 128, 2048, 128, 2048,
             2048, 1024, 2048, 1.0f);
    }

    // ---- o2 = o @ inv(Tv); out = fake_quant(o2) @ fake_quant(Wo)^T --------
    for (int h = 0; h < H; ++h)
        gemm(false, o + h * 128, invTv, o2 + h * 128, 2048, 128, 128, 2048, 128, 2048, 1.0f);
    rowquant_kernel<<<2048, TPB, 0, stream>>>(o2, o2, 2048);
    rowquant_kernel<<<2048, TPB, 0, stream>>>(Wo, WoQ, 2048);
    gemm(true, o2, WoQ, out, 2048, 2048, 2048, 2048, 2048, 2048, 1.0f);

    (void)in_sizes; (void)n_in; (void)out_size; (void)ws_size;
}

// Round 3
// 1421.701 us; speedup vs baseline: 6.8556x; 3.3154x over previous
//
#include <hip/hip_runtime.h>
#include <math.h>

typedef unsigned short u16;
typedef __attribute__((ext_vector_type(8))) short bf16x8;
typedef __attribute__((ext_vector_type(4))) float f32x4;

__device__ __forceinline__ u16 f2bf(float x) {
    union { float f; unsigned int u; } c; c.f = x;
    unsigned int r = c.u + 0x7fffu + ((c.u >> 16) & 1u);
    return (u16)(r >> 16);
}
__device__ __forceinline__ float bf2f(u16 h) {
    union { unsigned int u; float f; } c; c.u = ((unsigned int)h) << 16;
    return c.f;
}

// ---------------- Gauss-Jordan inverse, 4 matrices padded to 128 -----------
__global__ __launch_bounds__(256) void gj4_kernel(
    const float* __restrict__ A0, float* __restrict__ I0,
    const float* __restrict__ A1, float* __restrict__ I1,
    const float* __restrict__ A2, float* __restrict__ I2,
    const float* __restrict__ A3, float* __restrict__ I3) {
    __shared__ float sA[128 * 128];
    __shared__ float rowb[128];
    __shared__ float colb[128];
    const float* A; float* out; int N;
    switch (blockIdx.x) {
        case 0:  A = A0; out = I0; N = 32;  break;
        case 1:  A = A1; out = I1; N = 64;  break;
        case 2:  A = A2; out = I2; N = 128; break;
        default: A = A3; out = I3; N = 128; break;
    }
    int tid = threadIdx.x;
    for (int idx = tid; idx < 16384; idx += 256) {
        int i = idx >> 7, j = idx & 127;
        sA[idx] = (i < N && j < N) ? A[i * N + j] : (i == j ? 1.0f : 0.0f);
    }
    __syncthreads();
    for (int k = 0; k < 128; ++k) {
        if (tid < 128) {
            float p = sA[(k << 7) + k];
            float ip = 1.0f / p;
            rowb[tid] = (tid == k) ? ip : sA[(k << 7) + tid] * ip;
            colb[tid] = sA[(tid << 7) + k];
        }
        __syncthreads();
        float4* s4 = (float4*)sA;
        float4* r4 = (float4*)rowb;
        int kc = k >> 2, km = k & 3;
        for (int q = tid; q < 4096; q += 256) {
            int i = q >> 5, c = q & 31;
            float4 v = s4[q];
            float4 rb = r4[c];
            if (i == k) {
                v = rb;
            } else {
                float ci = colb[i];
                float4 ov = v;
                v.x = fmaf(-ci, rb.x, v.x);
                v.y = fmaf(-ci, rb.y, v.y);
                v.z = fmaf(-ci, rb.z, v.z);
                v.w = fmaf(-ci, rb.w, v.w);
                if (c == kc) {
                    float o_ = (km == 0 ? ov.x : km == 1 ? ov.y : km == 2 ? ov.z : ov.w);
                    if (km == 0) v.x -= o_; else if (km == 1) v.y -= o_;
                    else if (km == 2) v.z -= o_; else v.w -= o_;
                }
            }
            s4[q] = v;
        }
        __syncthreads();
    }
    for (int idx = tid; idx < N * N; idx += 256) {
        int i = idx / N, j = idx % N;
        out[idx] = sA[(i << 7) + j];
    }
}

// ---------------- split fp32 -> (hi, lo) bf16 planes -----------------------
__global__ void split_kernel(const float* __restrict__ in, u16* __restrict__ hi,
                             u16* __restrict__ lo, int n) {
    int idx = (blockIdx.x * 256 + threadIdx.x) * 4;
    if (idx >= n) return;
    float4 v = *(const float4*)(in + idx);
    ushort4 h, l;
    h.x = f2bf(v.x); l.x = f2bf(v.x - bf2f(h.x));
    h.y = f2bf(v.y); l.y = f2bf(v.y - bf2f(h.y));
    h.z = f2bf(v.z); l.z = f2bf(v.z - bf2f(h.z));
    h.w = f2bf(v.w); l.w = f2bf(v.w - bf2f(h.w));
    *(ushort4*)(hi + idx) = h;
    *(ushort4*)(lo + idx) = l;
}

// ---------------- transpose + split: out[c][r] = in[r][c] ------------------
__global__ void split_t_kernel(const float* __restrict__ in, u16* __restrict__ hi,
                               u16* __restrict__ lo, int rows, int cols) {
    __shared__ float t[32][33];
    int bx = blockIdx.x, by = blockIdx.y;
    int lx = threadIdx.x & 31, ly = threadIdx.x >> 5;
    for (int r = ly; r < 32; r += 8)
        t[r][lx] = in[(size_t)(by * 32 + r) * cols + bx * 32 + lx];
    __syncthreads();
    for (int r = ly; r < 32; r += 8) {
        float v = t[lx][r];
        size_t o = (size_t)(bx * 32 + r) * rows + by * 32 + lx;
        u16 h = f2bf(v);
        hi[o] = h;
        lo[o] = f2bf(v - bf2f(h));
    }
}

// ---------------- build P^T and Pinv directly as split planes --------------
__global__ void build_PT_s_kernel(const float* __restrict__ L, const float* __restrict__ R,
                                  const float* __restrict__ dg, u16* __restrict__ hi,
                                  u16* __restrict__ lo) {
    int idx = blockIdx.x * 256 + threadIdx.x;
    int j = idx >> 11, i = idx & 2047;
    float v = dg[i] * L[(i >> 6) * 32 + (j >> 6)] * R[((i & 63) << 6) + (j & 63)];
    u16 h = f2bf(v); hi[idx] = h; lo[idx] = f2bf(v - bf2f(h));
}
__global__ void build_Pinv_s_kernel(const float* __restrict__ invL, const float* __restrict__ invR,
                                    const float* __restrict__ dg, u16* __restrict__ hi,
                                    u16* __restrict__ lo) {
    int idx = blockIdx.x * 256 + threadIdx.x;
    int i = idx >> 11, j = idx & 2047;
    float v = invL[(i >> 6) * 32 + (j >> 6)] * invR[((i & 63) << 6) + (j & 63)] / dg[j];
    u16 h = f2bf(v); hi[idx] = h; lo[idx] = f2bf(v - bf2f(h));
}

// ---------------- split-bf16 MFMA GEMM: C = alpha * A * B^T ----------------
// A: [M][K] hi/lo planes (lda), B: [N][K] hi/lo planes (ldb).
// batched via grid.z: operand offset = (z >> div) * zStride.
// CAUSAL: 0 none; 1 skip tiles with n0 > m0 (QK^T); 2 trim K to m0+128 (PV).
template <bool SPLIT_OUT, int CAUSAL>
__global__ __launch_bounds__(256) void gemm_kernel(
    const u16* __restrict__ Ah, const u16* __restrict__ Al, int lda, long aZ, int aDiv,
    const u16* __restrict__ Bh, const u16* __restrict__ Bl, int ldb, long bZ, int bDiv,
    float* __restrict__ C, u16* __restrict__ Ch, u16* __restrict__ Cl,
    int ldc, long cZ, int cDiv, int K, float alpha) {
    const int m0 = blockIdx.y * 128, n0 = blockIdx.x * 128;
    if (CAUSAL == 1 && n0 > m0) return;
    const int z = blockIdx.z;
    {
        long ao = (long)(z >> aDiv) * aZ;
        long bo = (long)(z >> bDiv) * bZ;
        Ah += ao; Al += ao; Bh += bo; Bl += bo;
    }
    const int Keff = (CAUSAL == 2) ? (K < m0 + 128 ? K : m0 + 128) : K;

    __shared__ u16 Ash[2][2][128][36];
    __shared__ u16 Bsh[2][2][128][36];

    const int tid = threadIdx.x, lane = tid & 63, wave = tid >> 6;
    const int wr = wave >> 1, wc = wave & 1;
    const int fr = lane & 15, fg8 = (lane >> 4) * 8;
    const int srow = tid >> 2, cc8 = (tid & 3) * 8;

    f32x4 acc[4][4];
#pragma unroll
    for (int m = 0; m < 4; ++m)
#pragma unroll
        for (int n = 0; n < 4; ++n) acc[m][n] = (f32x4)0.0f;

    uint4 rah0, rah1, ral0, ral1, rbh0, rbh1, rbl0, rbl1;
    const size_t aoff0 = (size_t)(m0 + srow) * lda + cc8;
    const size_t aoff1 = aoff0 + (size_t)64 * lda;
    const size_t boff0 = (size_t)(n0 + srow) * ldb + cc8;
    const size_t boff1 = boff0 + (size_t)64 * ldb;

#define G_LOAD(k0) { \
    rah0 = *(const uint4*)(Ah + aoff0 + (k0)); rah1 = *(const uint4*)(Ah + aoff1 + (k0)); \
    ral0 = *(const uint4*)(Al + aoff0 + (k0)); ral1 = *(const uint4*)(Al + aoff1 + (k0)); \
    rbh0 = *(const uint4*)(Bh + boff0 + (k0)); rbh1 = *(const uint4*)(Bh + boff1 + (k0)); \
    rbl0 = *(const uint4*)(Bl + boff0 + (k0)); rbl1 = *(const uint4*)(Bl + boff1 + (k0)); }
#define ST8(dst, r) { *(uint2*)(dst) = make_uint2((r).x, (r).y); \
                      *(uint2*)((dst) + 4) = make_uint2((r).z, (r).w); }
#define G_STORE(b) { \
    ST8(&Ash[b][0][srow][cc8], rah0); ST8(&Ash[b][0][srow + 64][cc8], rah1); \
    ST8(&Ash[b][1][srow][cc8], ral0); ST8(&Ash[b][1][srow + 64][cc8], ral1); \
    ST8(&Bsh[b][0][srow][cc8], rbh0); ST8(&Bsh[b][0][srow + 64][cc8], rbh1); \
    ST8(&Bsh[b][1][srow][cc8], rbl0); ST8(&Bsh[b][1][srow + 64][cc8], rbl1); }

    const int nk = Keff >> 5;
    G_LOAD(0);
    G_STORE(0);
    __syncthreads();
    int cur = 0;
    for (int ik = 0; ik < nk; ++ik) {
        if (ik + 1 < nk) G_LOAD((ik + 1) << 5);
        bf16x8 bh[4], bl[4];
#pragma unroll
        for (int n = 0; n < 4; ++n) {
            const u16* p = &Bsh[cur][0][wc * 64 + n * 16 + fr][fg8];
            ((uint2*)&bh[n])[0] = *(const uint2*)p;
            ((uint2*)&bh[n])[1] = *(const uint2*)(p + 4);
            const u16* q = &Bsh[cur][1][wc * 64 + n * 16 + fr][fg8];
            ((uint2*)&bl[n])[0] = *(const uint2*)q;
            ((uint2*)&bl[n])[1] = *(const uint2*)(q + 4);
        }
#pragma unroll
        for (int m = 0; m < 4; ++m) {
            bf16x8 ah, al;
            const u16* p = &Ash[cur][0][wr * 64 + m * 16 + fr][fg8];
            ((uint2*)&ah)[0] = *(const uint2*)p;
            ((uint2*)&ah)[1] = *(const uint2*)(p + 4);
            const u16* q = &Ash[cur][1][wr * 64 + m * 16 + fr][fg8];
            ((uint2*)&al)[0] = *(const uint2*)q;
            ((uint2*)&al)[1] = *(const uint2*)(q + 4);
#pragma unroll
            for (int n = 0; n < 4; ++n) {
                acc[m][n] = __builtin_amdgcn_mfma_f32_16x16x32_bf16(ah, bh[n], acc[m][n], 0, 0, 0);
                acc[m][n] = __builtin_amdgcn_mfma_f32_16x16x32_bf16(ah, bl[n], acc[m][n], 0, 0, 0);
                acc[m][n] = __builtin_amdgcn_mfma_f32_16x16x32_bf16(al, bh[n], acc[m][n], 0, 0, 0);
            }
        }
        if (ik + 1 < nk) G_STORE(cur ^ 1);
        __syncthreads();
        cur ^= 1;
    }
    const long co = (long)(z >> cDiv) * cZ;
#pragma unroll
    for (int m = 0; m < 4; ++m) {
        int row_b = m0 + wr * 64 + m * 16 + (fg8 >> 1);
#pragma unroll
        for (int n = 0; n < 4; ++n) {
            int col = n0 + wc * 64 + n * 16 + fr;
#pragma unroll
            for (int j = 0; j < 4; ++j) {
                long o = co + (long)(row_b + j) * ldc + col;
                float v = alpha * acc[m][n][j];
                if (SPLIT_OUT) {
                    u16 h = f2bf(v);
                    Ch[o] = h;
                    Cl[o] = f2bf(v - bf2f(h));
                } else {
                    C[o] = v;
                }
            }
        }
    }
#undef G_LOAD
#undef G_STORE
#undef ST8
}

// ---------------- per-row fake_quant -> fp32 in place ----------------------
__global__ void rowquant_kernel(float* __restrict__ x, int cols) {
    __shared__ float red[256];
    int row = blockIdx.x, tid = threadIdx.x;
    float* p = x + (size_t)row * cols;
    float m = 0.0f;
    for (int j = tid; j < cols; j += 256) m = fmaxf(m, fabsf(p[j]));
    red[tid] = m; __syncthreads();
    for (int s = 128; s > 0; s >>= 1) {
        if (tid < s) red[tid] = fmaxf(red[tid], red[tid + s]);
        __syncthreads();
    }
    float scale = fmaxf(red[0] / 127.0f, 1e-8f);
    for (int j = tid; j < cols; j += 256) {
        float q = rintf(p[j] / scale);
        q = fminf(fmaxf(q, -127.0f), 127.0f);
        p[j] = q * scale;
    }
}

// ---------------- per-row fake_quant -> split planes -----------------------
__global__ void rowquant_split_kernel(const float* __restrict__ x, u16* __restrict__ hi,
                                      u16* __restrict__ lo, int cols) {
    __shared__ float red[256];
    int row = blockIdx.x, tid = threadIdx.x;
    const float* p = x + (size_t)row * cols;
    u16* ph = hi + (size_t)row * cols;
    u16* pl = lo + (size_t)row * cols;
    float m = 0.0f;
    for (int j = tid; j < cols; j += 256) m = fmaxf(m, fabsf(p[j]));
    red[tid] = m; __syncthreads();
    for (int s = 128; s > 0; s >>= 1) {
        if (tid < s) red[tid] = fmaxf(red[tid], red[tid + s]);
        __syncthreads();
    }
    float scale = fmaxf(red[0] / 127.0f, 1e-8f);
    for (int j = tid; j < cols; j += 256) {
        float q = rintf(p[j] / scale);
        q = fminf(fmaxf(q, -127.0f), 127.0f);
        float v = q * scale;
        u16 h = f2bf(v);
        ph[j] = h;
        pl[j] = f2bf(v - bf2f(h));
    }
}

// ---------------- RoPE in place, x:(S, nh, 128), cos/sin:(S,128) -----------
__global__ void rope_kernel(float* __restrict__ x, const float* __restrict__ c,
                            const float* __restrict__ s, int nh) {
    int idx = blockIdx.x * 256 + threadIdx.x;
    int d = idx & 63;
    int t = idx >> 6;
    int h = t % nh;
    int sq = t / nh;
    size_t base = ((size_t)sq * nh + h) * 128;
    float a = x[base + d], b = x[base + d + 64];
    float c1 = c[sq * 128 + d], s1 = s[sq * 128 + d];
    float c2 = c[sq * 128 + d + 64], s2 = s[sq * 128 + d + 64];
    x[base + d] = a * c1 - b * s1;
    x[base + d + 64] = b * c2 + a * s2;
}

// ---------------- causal softmax on split planes, in place -----------------
__global__ void softmax_split_kernel(u16* __restrict__ Sh, u16* __restrict__ Sl,
                                     long planeStride) {
    __shared__ float buf[2048];
    __shared__ float red[256];
    int qi = blockIdx.x, z = blockIdx.y, tid = threadIdx.x;
    u16* ph = Sh + (long)z * planeStride + (long)qi * 2048;
    u16* pl = Sl + (long)z * planeStride + (long)qi * 2048;
    int valid = qi + 1;
    float m = -3.0e38f;
    for (int j = tid; j < valid; j += 256) {
        float v = bf2f(ph[j]) + bf2f(pl[j]);
        buf[j] = v;
        m = fmaxf(m, v);
    }
    red[tid] = m; __syncthreads();
    for (int s = 128; s > 0; s >>= 1) {
        if (tid < s) red[tid] = fmaxf(red[tid], red[tid + s]);
        __syncthreads();
    }
    float rmax = red[0];
    __syncthreads();
    float sum = 0.0f;
    for (int j = tid; j < valid; j += 256) {
        float e = expf(buf[j] - rmax);
        buf[j] = e;
        sum += e;
    }
    red[tid] = sum; __syncthreads();
    for (int s = 128; s > 0; s >>= 1) {
        if (tid < s) red[tid] += red[tid + s];
        __syncthreads();
    }
    float inv = 1.0f / red[0];
    for (int j = tid; j < valid; j += 256) {
        float p = buf[j] * inv;
        u16 h = f2bf(p);
        ph[j] = h;
        pl[j] = f2bf(p - bf2f(h));
    }
    for (int j = valid + tid; j < 2048; j += 256) { ph[j] = 0; pl[j] = 0; }
}

// ===========================================================================
extern "C" void kernel_launch(void* const* d_in, const int* in_sizes, int n_in,
                              void* d_out, int out_size, void* d_ws, size_t ws_size,
                              hipStream_t stream) {
    const int S = 2048;
    const float* hidden = (const float*)d_in[0];
    const float* cosp   = (const float*)d_in[1];
    const float* sinp   = (const float*)d_in[2];
    const float* Wq     = (const float*)d_in[3];
    const float* Wk     = (const float*)d_in[4];
    const float* Wv     = (const float*)d_in[5];
    const float* Wo     = (const float*)d_in[6];
    const float* Lp     = (const float*)d_in[7];
    const float* Rp     = (const float*)d_in[8];
    const float* diag   = (const float*)d_in[9];
    const float* Tkp    = (const float*)d_in[10];
    const float* Tvp    = (const float*)d_in[11];
    float* out = (float*)d_out;

    const size_t MiB = 1ull << 20;
    char* W = (char*)d_ws;
    auto F = [&](size_t mb) { return (float*)(W + mb * MiB); };
    auto U = [&](size_t mb) { return (u16*)(W + mb * MiB); };

    // small scratch lives in d_out (final GEMM fully overwrites it)
    float* dsc   = (float*)d_out;
    float* invL  = dsc;            // 32*32
    float* invR  = dsc + 1024;     // 64*64
    float* invTk = dsc + 5120;     // 128*128
    float* invTv = dsc + 21504;    // 128*128
    u16* sm = (u16*)(dsc + 37888);
    u16* invTk_sh = sm;              u16* invTk_sl = sm + 16384;
    u16* TkT_sh   = sm + 2 * 16384;  u16* TkT_sl   = sm + 3 * 16384;
    u16* invTvT_sh= sm + 4 * 16384;  u16* invTvT_sl= sm + 5 * 16384;
    u16* TvT_sh   = sm + 6 * 16384;  u16* TvT_sl   = sm + 7 * 16384;

    // chunking of attention heads by available workspace
    int nh;
    if      (ws_size >= 312 * MiB) nh = 16;
    else if (ws_size >= 184 * MiB) nh = 8;
    else if (ws_size >= 112 * MiB) nh = 4;
    else                           nh = 2;

    const long PL = (long)S * S;          // score plane elems per head
    const long HP = 4194304;              // 2048*2048 plane elems
    const long HP2 = 2097152;             // 2048*1024

    // plane pair helper: base u16* p -> hi = p, lo = p + elems
    u16* PT_s   = U(0);    // [0,16)
    u16* PINV_s = U(16);   // [16,32)

    auto gemm = [&](int mode /*0 plain,1 qk,2 pv*/, dim3 grid,
                    const u16* Ah, const u16* Al, int lda, long aZ, int aDiv,
                    const u16* Bh, const u16* Bl, int ldb, long bZ, int bDiv,
                    float* C, u16* Ch, u16* Cl, int ldc, long cZ, int cDiv,
                    int K, float alpha) {
        if (mode == 0)
            gemm_kernel<false, 0><<<grid, 256, 0, stream>>>(Ah, Al, lda, aZ, aDiv,
                Bh, Bl, ldb, bZ, bDiv, C, Ch, Cl, ldc, cZ, cDiv, K, alpha);
        else if (mode == 1)
            gemm_kernel<true, 1><<<grid, 256, 0, stream>>>(Ah, Al, lda, aZ, aDiv,
                Bh, Bl, ldb, bZ, bDiv, C, Ch, Cl, ldc, cZ, cDiv, K, alpha);
        else
            gemm_kernel<false, 2><<<grid, 256, 0, stream>>>(Ah, Al, lda, aZ, aDiv,
                Bh, Bl, ldb, bZ, bDiv, C, Ch, Cl, ldc, cZ, cDiv, K, alpha);
    };

    // ---- P0: inverses + small splits ----
    gj4_kernel<<<4, 256, 0, stream>>>(Lp, invL, Rp, invR, Tkp, invTk, Tvp, invTv);
    split_kernel<<<16, 256, 0, stream>>>(invTk, invTk_sh, invTk_sl, 16384);
    split_t_kernel<<<dim3(4, 4), 256, 0, stream>>>(Tkp, TkT_sh, TkT_sl, 128, 128);
    split_t_kernel<<<dim3(4, 4), 256, 0, stream>>>(invTv, invTvT_sh, invTvT_sl, 128, 128);
    split_t_kernel<<<dim3(4, 4), 256, 0, stream>>>(Tvp, TvT_sh, TvT_sl, 128, 128);
    build_PT_s_kernel<<<16384, 256, 0, stream>>>(Lp, Rp, diag, PT_s, PT_s + HP);
    build_Pinv_s_kernel<<<16384, 256, 0, stream>>>(invL, invR, diag, PINV_s, PINV_s + HP);

    // ---- P1: weight prep ----
    u16* tmp_s = U(32);  // split input scratch [32,48)
    float* tmpf = F(48); // fp32 gemm out [48,64)
    u16* WQ_s = U(64);   // [64,80)
    u16* WK_s = U(80);   // [80,88)
    u16* WV_s = U(88);   // [88,96)

    split_kernel<<<4096, 256, 0, stream>>>(Wq, tmp_s, tmp_s + HP, 4194304);
    gemm(0, dim3(16, 16, 1), tmp_s, tmp_s + HP, 2048, 0, 0,
         PINV_s, PINV_s + HP, 2048, 0, 0, tmpf, 0, 0, 2048, 0, 0, 2048, 1.0f);
    rowquant_split_kernel<<<2048, 256, 0, stream>>>(tmpf, WQ_s, WQ_s + HP, 2048);

    split_kernel<<<2048, 256, 0, stream>>>(Wk, tmp_s, tmp_s + HP2, 2097152);
    gemm(0, dim3(16, 8, 1), tmp_s, tmp_s + HP2, 2048, 0, 0,
         PINV_s, PINV_s + HP, 2048, 0, 0, tmpf, 0, 0, 2048, 0, 0, 2048, 1.0f);
    rowquant_split_kernel<<<1024, 256, 0, stream>>>(tmpf, WK_s, WK_s + HP2, 2048);

    split_kernel<<<2048, 256, 0, stream>>>(Wv, tmp_s, tmp_s + HP2, 2097152);
    gemm(0, dim3(16, 8, 1), tmp_s, tmp_s + HP2, 2048, 0, 0,
         PINV_s, PINV_s + HP, 2048, 0, 0, tmpf, 0, 0, 2048, 0, 0, 2048, 1.0f);
    u16* WVPt_s = U(56); // [56,64)
    split_t_kernel<<<dim3(64, 32), 256, 0, stream>>>(tmpf, WVPt_s, WVPt_s + HP2, 1024, 2048);
    float* WVf = F(32);  // [32,40)
    gemm(0, dim3(16, 1, 8), TvT_sh, TvT_sl, 128, 0, 0,
         WVPt_s, WVPt_s + HP2, 1024, 128, 0, WVf, 0, 0, 2048, (long)128 * 2048, 0, 128, 1.0f);
    rowquant_split_kernel<<<1024, 256, 0, stream>>>(WVf, WV_s, WV_s + HP2, 2048);

    split_kernel<<<4096, 256, 0, stream>>>(hidden, tmp_s, tmp_s + HP, 4194304);
    gemm(0, dim3(16, 16, 1), tmp_s, tmp_s + HP, 2048, 0, 0,
         PT_s, PT_s + HP, 2048, 0, 0, tmpf, 0, 0, 2048, 0, 0, 2048, 1.0f);
    u16* X_s = U(0);     // [0,16) over PT_s (dead)
    rowquant_split_kernel<<<2048, 256, 0, stream>>>(tmpf, X_s, X_s + HP, 2048);

    // ---- P2: projections, RoPE, head transforms ----
    float* Qf  = F(16);  // [16,32) over PINV_s (dead)
    float* KBf = F(32);  // [32,40)
    float* Vf  = F(40);  // [40,48)
    gemm(0, dim3(16, 16, 1), X_s, X_s + HP, 2048, 0, 0,
         WQ_s, WQ_s + HP, 2048, 0, 0, Qf, 0, 0, 2048, 0, 0, 2048, 1.0f);
    gemm(0, dim3(8, 16, 1), X_s, X_s + HP, 2048, 0, 0,
         WK_s, WK_s + HP2, 2048, 0, 0, KBf, 0, 0, 1024, 0, 0, 2048, 1.0f);
    gemm(0, dim3(8, 16, 1), X_s, X_s + HP, 2048, 0, 0,
         WV_s, WV_s + HP2, 2048, 0, 0, Vf, 0, 0, 1024, 0, 0, 2048, 1.0f);

    rope_kernel<<<8192, 256, 0, stream>>>(Qf, cosp, sinp, 16);
    rope_kernel<<<4096, 256, 0, stream>>>(KBf, cosp, sinp, 8);

    u16* Q_s = U(48);    // [48,64)
    split_kernel<<<4096, 256, 0, stream>>>(Qf, Q_s, Q_s + HP, 4194304);
    float* q2f = F(16);  // over Qf (dead)
    gemm(0, dim3(1, 16, 16), Q_s, Q_s + HP, 2048, 128, 0,
         invTk_sh, invTk_sl, 128, 0, 0, q2f, 0, 0, 2048, 128, 0, 128, 1.0f);
    u16* q2_s = U(0);    // [0,16) over X_s (dead)
    split_kernel<<<4096, 256, 0, stream>>>(q2f, q2_s, q2_s + HP, 4194304);

    u16* KB_s = U(48);   // over Q_s (dead)
    split_kernel<<<2048, 256, 0, stream>>>(KBf, KB_s, KB_s + HP2, 2097152);
    float* k2f = F(32);  // over KBf (dead)
    gemm(0, dim3(1, 16, 8), KB_s, KB_s + HP2, 1024, 128, 0,
         TkT_sh, TkT_sl, 128, 0, 0, k2f, 0, 0, 1024, 128, 0, 128, 1.0f);
    u16* k2_s = U(32 + 16 * nh);
    rowquant_split_kernel<<<16384, 256, 0, stream>>>(k2f, k2_s, k2_s + HP2, 128);

    rowquant_kernel<<<16384, 256, 0, stream>>>(Vf, 128);
    u16* vT_s = U(40 + 16 * nh);
    split_t_kernel<<<dim3(32, 64), 256, 0, stream>>>(Vf, vT_s, vT_s + HP2, 2048, 1024);

    // ---- P3: attention in chunks of nh heads ----
    float* of = F(16);       // o, head-major [16][2048][128]
    u16* scores = U(32);     // nh hi planes then nh lo planes
    const float scale = 0.08838834764831845f;
    for (int c0 = 0; c0 < 16; c0 += nh) {
        gemm(1, dim3(16, 16, nh),
             q2_s + c0 * 128, q2_s + HP + c0 * 128, 2048, 128, 0,
             k2_s + (c0 >> 1) * 128, k2_s + HP2 + (c0 >> 1) * 128, 1024, 128, 1,
             0, scores, scores + (long)nh * PL, 2048, PL, 0, 128, scale);
        softmax_split_kernel<<<dim3(2048, nh), 256, 0, stream>>>(
             scores, scores + (long)nh * PL, PL);
        gemm(2, dim3(1, 16, nh),
             scores, scores + (long)nh * PL, 2048, PL, 0,
             vT_s + (long)(c0 >> 1) * 128 * 2048, vT_s + HP2 + (long)(c0 >> 1) * 128 * 2048,
             2048, (long)128 * 2048, 1,
             of + (long)c0 * 262144, 0, 0, 128, 262144, 0, 2048, 1.0f);
    }

    // ---- P4: output transform + final projection ----
    u16* o_s = U(32);
    split_kernel<<<4096, 256, 0, stream>>>(of, o_s, o_s + HP, 4194304);
    float* o2f = F(48);
    gemm(0, dim3(1, 16, 16), o_s, o_s + HP, 128, 262144, 0,
         invTvT_sh, invTvT_sl, 128, 0, 0, o2f, 0, 0, 2048, 128, 0, 128, 1.0f);
    u16* o2q_s = U(64);
    rowquant_split_kernel<<<2048, 256, 0, stream>>>(o2f, o2q_s, o2q_s + HP, 2048);
    u16* Wo_s = U(80);
    rowquant_split_kernel<<<2048, 256, 0, stream>>>(Wo, Wo_s, Wo_s + HP, 2048);
    gemm(0, dim3(16, 16, 1), o2q_s, o2q_s + HP, 2048, 0, 0,
         Wo_s, Wo_s + HP, 2048, 0, 0, out, 0, 0, 2048, 0, 0, 2048, 1.0f);

    (void)in_sizes; (void)n_in; (void)out_size;
}

// Round 4
// 1187.311 us; speedup vs baseline: 8.2090x; 1.1974x over previous
//
#include <hip/hip_runtime.h>
#include <math.h>

typedef unsigned short u16;
typedef __attribute__((ext_vector_type(8))) short bf16x8;
typedef __attribute__((ext_vector_type(4))) float f32x4;

__device__ __forceinline__ u16 f2bf(float x) {
    union { float f; unsigned int u; } c; c.f = x;
    unsigned int r = c.u + 0x7fffu + ((c.u >> 16) & 1u);
    return (u16)(r >> 16);
}
__device__ __forceinline__ float bf2f(u16 h) {
    union { unsigned int u; float f; } c; c.u = ((unsigned int)h) << 16;
    return c.f;
}
__device__ __forceinline__ bf16x8 ld16(const u16* p) {
    bf16x8 r;
    ((uint2*)&r)[0] = *(const uint2*)p;
    ((uint2*)&r)[1] = *(const uint2*)(p + 4);
    return r;
}

// ---------------- register-resident Gauss-Jordan, 4 matrices ---------------
// 1024 threads: thread owns row i = tid>>3, cols (tid&7)*16 .. +15 in VGPRs.
__global__ __launch_bounds__(1024) void gj4_kernel(
    const float* __restrict__ A0, float* __restrict__ I0,
    const float* __restrict__ A1, float* __restrict__ I1,
    const float* __restrict__ A2, float* __restrict__ I2,
    const float* __restrict__ A3, float* __restrict__ I3) {
    __shared__ float rowbuf[2][128];
    __shared__ float colbuf[2][128];
    const float* A; float* out; int N;
    switch (blockIdx.x) {
        case 0:  A = A0; out = I0; N = 32;  break;
        case 1:  A = A1; out = I1; N = 64;  break;
        case 2:  A = A2; out = I2; N = 128; break;
        default: A = A3; out = I3; N = 128; break;
    }
    const int tid = threadIdx.x;
    const int i = tid >> 3, c0 = (tid & 7) * 16;
    float r[16];
#pragma unroll
    for (int e = 0; e < 16; ++e) {
        int j = c0 + e;
        r[e] = (i < N && j < N) ? A[i * N + j] : (i == j ? 1.0f : 0.0f);
    }
    if ((tid & 7) == 0) colbuf[0][i] = r[0];
    __syncthreads();
    for (int k = 0; k < 128; ++k) {
        int pb = k & 1;
        if (i == k) {
            float ip = 1.0f / colbuf[pb][k];
#pragma unroll
            for (int e = 0; e < 16; ++e)
                rowbuf[pb][c0 + e] = (c0 + e == k) ? ip : r[e] * ip;
        }
        __syncthreads();
        float ci = colbuf[pb][i];
        float rb[16];
#pragma unroll
        for (int e = 0; e < 16; ++e) rb[e] = rowbuf[pb][c0 + e];
        if (i == k) {
#pragma unroll
            for (int e = 0; e < 16; ++e) r[e] = rb[e];
        } else {
#pragma unroll
            for (int e = 0; e < 16; ++e) {
                float v = (c0 + e == k) ? 0.0f : r[e];
                r[e] = fmaf(-ci, rb[e], v);
            }
        }
        if (k + 1 < 128 && ((k + 1) >> 4) == (tid & 7))
            colbuf[(k + 1) & 1][i] = r[(k + 1) & 15];
        __syncthreads();
    }
    if (i < N)
#pragma unroll
        for (int e = 0; e < 16; ++e) {
            int j = c0 + e;
            if (j < N) out[i * N + j] = r[e];
        }
}

// ---------------- split fp32 -> (hi, lo) bf16 planes -----------------------
__global__ void split_kernel(const float* __restrict__ in, u16* __restrict__ hi,
                             u16* __restrict__ lo, int n) {
    int idx = (blockIdx.x * 256 + threadIdx.x) * 4;
    if (idx >= n) return;
    float4 v = *(const float4*)(in + idx);
    ushort4 h, l;
    h.x = f2bf(v.x); l.x = f2bf(v.x - bf2f(h.x));
    h.y = f2bf(v.y); l.y = f2bf(v.y - bf2f(h.y));
    h.z = f2bf(v.z); l.z = f2bf(v.z - bf2f(h.z));
    h.w = f2bf(v.w); l.w = f2bf(v.w - bf2f(h.w));
    *(ushort4*)(hi + idx) = h;
    *(ushort4*)(lo + idx) = l;
}

// ---------------- transpose + split: out[c][r] = in[r][c] ------------------
__global__ void split_t_kernel(const float* __restrict__ in, u16* __restrict__ hi,
                               u16* __restrict__ lo, int rows, int cols) {
    __shared__ float t[32][33];
    int bx = blockIdx.x, by = blockIdx.y;
    int lx = threadIdx.x & 31, ly = threadIdx.x >> 5;
    for (int r = ly; r < 32; r += 8)
        t[r][lx] = in[(size_t)(by * 32 + r) * cols + bx * 32 + lx];
    __syncthreads();
    for (int r = ly; r < 32; r += 8) {
        float v = t[lx][r];
        size_t o = (size_t)(bx * 32 + r) * rows + by * 32 + lx;
        u16 h = f2bf(v);
        hi[o] = h;
        lo[o] = f2bf(v - bf2f(h));
    }
}

// ---------------- build P^T and Pinv directly as split planes --------------
__global__ void build_PT_s_kernel(const float* __restrict__ L, const float* __restrict__ R,
                                  const float* __restrict__ dg, u16* __restrict__ hi,
                                  u16* __restrict__ lo) {
    int idx = blockIdx.x * 256 + threadIdx.x;
    int j = idx >> 11, i = idx & 2047;
    float v = dg[i] * L[(i >> 6) * 32 + (j >> 6)] * R[((i & 63) << 6) + (j & 63)];
    u16 h = f2bf(v); hi[idx] = h; lo[idx] = f2bf(v - bf2f(h));
}
__global__ void build_Pinv_s_kernel(const float* __restrict__ invL, const float* __restrict__ invR,
                                    const float* __restrict__ dg, u16* __restrict__ hi,
                                    u16* __restrict__ lo) {
    int idx = blockIdx.x * 256 + threadIdx.x;
    int i = idx >> 11, j = idx & 2047;
    float v = invL[(i >> 6) * 32 + (j >> 6)] * invR[((i & 63) << 6) + (j & 63)] / dg[j];
    u16 h = f2bf(v); hi[idx] = h; lo[idx] = f2bf(v - bf2f(h));
}

// ---------------- split-bf16 MFMA GEMM: C = alpha * A * B^T (fp32 out) -----
__global__ __launch_bounds__(256) void gemm_kernel(
    const u16* __restrict__ Ah, const u16* __restrict__ Al, int lda, long aZ, int aDiv,
    const u16* __restrict__ Bh, const u16* __restrict__ Bl, int ldb, long bZ, int bDiv,
    float* __restrict__ C, int ldc, long cZ, int cDiv, int K, float alpha) {
    const int m0 = blockIdx.y * 128, n0 = blockIdx.x * 128;
    const int z = blockIdx.z;
    {
        long ao = (long)(z >> aDiv) * aZ;
        long bo = (long)(z >> bDiv) * bZ;
        Ah += ao; Al += ao; Bh += bo; Bl += bo;
    }
    __shared__ u16 Ash[2][2][128][36];
    __shared__ u16 Bsh[2][2][128][36];

    const int tid = threadIdx.x, lane = tid & 63, wave = tid >> 6;
    const int wr = wave >> 1, wc = wave & 1;
    const int fr = lane & 15, fg8 = (lane >> 4) * 8;
    const int srow = tid >> 2, cc8 = (tid & 3) * 8;

    f32x4 acc[4][4];
#pragma unroll
    for (int m = 0; m < 4; ++m)
#pragma unroll
        for (int n = 0; n < 4; ++n) acc[m][n] = (f32x4)0.0f;

    uint4 rah0, rah1, ral0, ral1, rbh0, rbh1, rbl0, rbl1;
    const size_t aoff0 = (size_t)(m0 + srow) * lda + cc8;
    const size_t aoff1 = aoff0 + (size_t)64 * lda;
    const size_t boff0 = (size_t)(n0 + srow) * ldb + cc8;
    const size_t boff1 = boff0 + (size_t)64 * ldb;

#define G_LOAD(k0) { \
    rah0 = *(const uint4*)(Ah + aoff0 + (k0)); rah1 = *(const uint4*)(Ah + aoff1 + (k0)); \
    ral0 = *(const uint4*)(Al + aoff0 + (k0)); ral1 = *(const uint4*)(Al + aoff1 + (k0)); \
    rbh0 = *(const uint4*)(Bh + boff0 + (k0)); rbh1 = *(const uint4*)(Bh + boff1 + (k0)); \
    rbl0 = *(const uint4*)(Bl + boff0 + (k0)); rbl1 = *(const uint4*)(Bl + boff1 + (k0)); }
#define ST8(dst, r) { *(uint2*)(dst) = make_uint2((r).x, (r).y); \
                      *(uint2*)((dst) + 4) = make_uint2((r).z, (r).w); }
#define G_STORE(b) { \
    ST8(&Ash[b][0][srow][cc8], rah0); ST8(&Ash[b][0][srow + 64][cc8], rah1); \
    ST8(&Ash[b][1][srow][cc8], ral0); ST8(&Ash[b][1][srow + 64][cc8], ral1); \
    ST8(&Bsh[b][0][srow][cc8], rbh0); ST8(&Bsh[b][0][srow + 64][cc8], rbh1); \
    ST8(&Bsh[b][1][srow][cc8], rbl0); ST8(&Bsh[b][1][srow + 64][cc8], rbl1); }

    const int nk = K >> 5;
    G_LOAD(0);
    G_STORE(0);
    __syncthreads();
    int cur = 0;
    for (int ik = 0; ik < nk; ++ik) {
        if (ik + 1 < nk) G_LOAD((ik + 1) << 5);
        bf16x8 bh[4], bl[4];
#pragma unroll
        for (int n = 0; n < 4; ++n) {
            bh[n] = ld16(&Bsh[cur][0][wc * 64 + n * 16 + fr][fg8]);
            bl[n] = ld16(&Bsh[cur][1][wc * 64 + n * 16 + fr][fg8]);
        }
#pragma unroll
        for (int m = 0; m < 4; ++m) {
            bf16x8 ah = ld16(&Ash[cur][0][wr * 64 + m * 16 + fr][fg8]);
            bf16x8 al = ld16(&Ash[cur][1][wr * 64 + m * 16 + fr][fg8]);
#pragma unroll
            for (int n = 0; n < 4; ++n) {
                acc[m][n] = __builtin_amdgcn_mfma_f32_16x16x32_bf16(ah, bh[n], acc[m][n], 0, 0, 0);
                acc[m][n] = __builtin_amdgcn_mfma_f32_16x16x32_bf16(ah, bl[n], acc[m][n], 0, 0, 0);
                acc[m][n] = __builtin_amdgcn_mfma_f32_16x16x32_bf16(al, bh[n], acc[m][n], 0, 0, 0);
            }
        }
        if (ik + 1 < nk) G_STORE(cur ^ 1);
        __syncthreads();
        cur ^= 1;
    }
    const long co = (long)(z >> cDiv) * cZ;
#pragma unroll
    for (int m = 0; m < 4; ++m) {
        int row_b = m0 + wr * 64 + m * 16 + (fg8 >> 1);
#pragma unroll
        for (int n = 0; n < 4; ++n) {
            int col = n0 + wc * 64 + n * 16 + fr;
#pragma unroll
            for (int j = 0; j < 4; ++j)
                C[co + (long)(row_b + j) * ldc + col] = alpha * acc[m][n][j];
        }
    }
#undef G_LOAD
#undef G_STORE
#undef ST8
}

// ---------------- flash attention ------------------------------------------
// grid (16 heads, 32 q-tiles of 64). 256 thr = 4 waves, wave w: 16 q-rows.
// q2f fp32 [2048][2048]; k2 split [2048][1024]; vT split [1024][2048];
// o fp32 [16][2048][128].
__global__ __launch_bounds__(256) void flash_kernel(
    const float* __restrict__ q2f,
    const u16* __restrict__ k2h, const u16* __restrict__ k2l,
    const u16* __restrict__ vTh, const u16* __restrict__ vTl,
    float* __restrict__ o) {
    const int h = blockIdx.x, qt = blockIdx.y, g = h >> 1;
    __shared__ u16 Ksh[2 * 64 * 128];   // [plane][kv 64][d 128] swizzled
    __shared__ u16 Vsh[2 * 128 * 64];   // [plane][d 128][kv 64] swizzled
    __shared__ u16 Psh[4 * 16 * 64];    // [wave][row 16][kv 64] swizzled, hi only

    const int tid = threadIdx.x, lane = tid & 63, w = tid >> 6;
    const int lc = lane & 15, lg = lane >> 4;
    const float scale = 0.08838834764831845f;

    // ---- Q fragments (scale folded), split in-register ----
    bf16x8 qh[4], ql[4];
    {
        int s = qt * 64 + w * 16 + lc;
        const float* qp = q2f + (size_t)s * 2048 + h * 128 + lg * 8;
#pragma unroll
        for (int kk = 0; kk < 4; ++kk) {
            float4 v0 = *(const float4*)(qp + kk * 32);
            float4 v1 = *(const float4*)(qp + kk * 32 + 4);
            float vv[8] = {v0.x, v0.y, v0.z, v0.w, v1.x, v1.y, v1.z, v1.w};
#pragma unroll
            for (int e = 0; e < 8; ++e) {
                float x = vv[e] * scale;
                u16 hh = f2bf(x);
                qh[kk][e] = (short)hh;
                ql[kk][e] = (short)f2bf(x - bf2f(hh));
            }
        }
    }

    f32x4 acc_o[8];
#pragma unroll
    for (int nn = 0; nn < 8; ++nn) acc_o[nn] = (f32x4)0.0f;
    float mj[4] = {-1e30f, -1e30f, -1e30f, -1e30f};
    float lj[4] = {0.0f, 0.0f, 0.0f, 0.0f};

    for (int t = 0; t <= qt; ++t) {
        const int j0 = t * 64;
        // ---- stage K [64][128] and V^T [128][64], both planes, swizzled ----
        for (int ii = tid; ii < 2048; ii += 256) {
            int p = ii >> 10, q = ii & 1023;
            int r = q >> 4, c4 = q & 15;
            const u16* src = (p ? k2l : k2h) + (size_t)(j0 + r) * 1024 + g * 128 + c4 * 8;
            *(uint4*)(&Ksh[p * 8192 + r * 128 + ((c4 ^ (r & 7)) << 3)]) = *(const uint4*)src;
        }
        for (int ii = tid; ii < 2048; ii += 256) {
            int p = ii >> 10, q = ii & 1023;
            int d = q >> 3, c4 = q & 7;
            const u16* src = (p ? vTl : vTh) + (size_t)(g * 128 + d) * 2048 + j0 + c4 * 8;
            *(uint4*)(&Vsh[p * 8192 + d * 64 + ((c4 ^ (d & 7)) << 3)]) = *(const uint4*)src;
        }
        __syncthreads();

        // ---- QK^T (3-MFMA split) ----
        f32x4 accs[4];
#pragma unroll
        for (int n = 0; n < 4; ++n) accs[n] = (f32x4)0.0f;
        const int nlim = (t == qt) ? w : 3;
        for (int n = 0; n <= nlim; ++n) {
#pragma unroll
            for (int kk = 0; kk < 4; ++kk) {
                int roff = (n * 16 + lc) * 128 + (((kk * 4 + lg) ^ (lc & 7)) << 3);
                bf16x8 kh = ld16(&Ksh[roff]);
                bf16x8 kl = ld16(&Ksh[8192 + roff]);
                accs[n] = __builtin_amdgcn_mfma_f32_16x16x32_bf16(qh[kk], kh, accs[n], 0, 0, 0);
                accs[n] = __builtin_amdgcn_mfma_f32_16x16x32_bf16(qh[kk], kl, accs[n], 0, 0, 0);
                accs[n] = __builtin_amdgcn_mfma_f32_16x16x32_bf16(ql[kk], kh, accs[n], 0, 0, 0);
            }
        }
        if (t == qt) {
#pragma unroll
            for (int j = 0; j < 4; ++j)
                if (lc > lg * 4 + j) accs[w][j] = -1e30f;
        }

        // ---- online softmax ----
        float sf[4], rs[4];
#pragma unroll
        for (int j = 0; j < 4; ++j) {
            float v = accs[0][j];
            for (int n = 1; n <= nlim; ++n) v = fmaxf(v, accs[n][j]);
            v = fmaxf(v, __shfl_xor(v, 1));
            v = fmaxf(v, __shfl_xor(v, 2));
            v = fmaxf(v, __shfl_xor(v, 4));
            v = fmaxf(v, __shfl_xor(v, 8));
            float mn = fmaxf(mj[j], v);
            sf[j] = __expf(mj[j] - mn);
            mj[j] = mn;
            rs[j] = 0.0f;
        }
        for (int n = 0; n <= nlim; ++n)
#pragma unroll
            for (int j = 0; j < 4; ++j) {
                float p = __expf(accs[n][j] - mj[j]);
                accs[n][j] = p;
                rs[j] += p;
            }
#pragma unroll
        for (int j = 0; j < 4; ++j) {
            float v = rs[j];
            v += __shfl_xor(v, 1);
            v += __shfl_xor(v, 2);
            v += __shfl_xor(v, 4);
            v += __shfl_xor(v, 8);
            lj[j] = lj[j] * sf[j] + v;
        }
#pragma unroll
        for (int nn = 0; nn < 8; ++nn)
#pragma unroll
            for (int j = 0; j < 4; ++j) acc_o[nn][j] *= sf[j];

        // ---- write P (hi only) to wave-private LDS, C-layout -> A-layout ----
#pragma unroll
        for (int n = 0; n < 4; ++n)
#pragma unroll
            for (int j = 0; j < 4; ++j) {
                int rr = lg * 4 + j, c = n * 16 + lc;
                u16 val = (n <= nlim) ? f2bf(accs[n][j]) : (u16)0;
                Psh[w * 1024 + rr * 64 + (((c >> 3) ^ (rr & 7)) << 3) + (c & 7)] = val;
            }
        bf16x8 pf[2];
#pragma unroll
        for (int kk = 0; kk < 2; ++kk)
            pf[kk] = ld16(&Psh[w * 1024 + lc * 64 + (((kk * 4 + lg) ^ (lc & 7)) << 3)]);

        // ---- PV ----
#pragma unroll
        for (int nn = 0; nn < 8; ++nn) {
#pragma unroll
            for (int kk = 0; kk < 2; ++kk) {
                int voff = (nn * 16 + lc) * 64 + (((kk * 4 + lg) ^ (lc & 7)) << 3);
                bf16x8 vh = ld16(&Vsh[voff]);
                bf16x8 vl = ld16(&Vsh[8192 + voff]);
                acc_o[nn] = __builtin_amdgcn_mfma_f32_16x16x32_bf16(pf[kk], vh, acc_o[nn], 0, 0, 0);
                acc_o[nn] = __builtin_amdgcn_mfma_f32_16x16x32_bf16(pf[kk], vl, acc_o[nn], 0, 0, 0);
            }
        }
        __syncthreads();
    }

    // ---- epilogue: normalize + store ----
    float linv[4];
#pragma unroll
    for (int j = 0; j < 4; ++j) linv[j] = 1.0f / lj[j];
#pragma unroll
    for (int nn = 0; nn < 8; ++nn)
#pragma unroll
        for (int j = 0; j < 4; ++j) {
            int s = qt * 64 + w * 16 + lg * 4 + j;
            o[((size_t)h * 2048 + s) * 128 + nn * 16 + lc] = acc_o[nn][j] * linv[j];
        }
}

// ---------------- per-row fake_quant -> fp32 in place ----------------------
__global__ void rowquant_kernel(float* __restrict__ x, int cols) {
    __shared__ float red[256];
    int row = blockIdx.x, tid = threadIdx.x;
    float* p = x + (size_t)row * cols;
    float m = 0.0f;
    for (int j = tid; j < cols; j += 256) m = fmaxf(m, fabsf(p[j]));
    red[tid] = m; __syncthreads();
    for (int s = 128; s > 0; s >>= 1) {
        if (tid < s) red[tid] = fmaxf(red[tid], red[tid + s]);
        __syncthreads();
    }
    float scale = fmaxf(red[0] / 127.0f, 1e-8f);
    for (int j = tid; j < cols; j += 256) {
        float q = rintf(p[j] / scale);
        q = fminf(fmaxf(q, -127.0f), 127.0f);
        p[j] = q * scale;
    }
}

// ---------------- per-row fake_quant -> split planes -----------------------
__global__ void rowquant_split_kernel(const float* __restrict__ x, u16* __restrict__ hi,
                                      u16* __restrict__ lo, int cols) {
    __shared__ float red[256];
    int row = blockIdx.x, tid = threadIdx.x;
    const float* p = x + (size_t)row * cols;
    u16* ph = hi + (size_t)row * cols;
    u16* pl = lo + (size_t)row * cols;
    float m = 0.0f;
    for (int j = tid; j < cols; j += 256) m = fmaxf(m, fabsf(p[j]));
    red[tid] = m; __syncthreads();
    for (int s = 128; s > 0; s >>= 1) {
        if (tid < s) red[tid] = fmaxf(red[tid], red[tid + s]);
        __syncthreads();
    }
    float scale = fmaxf(red[0] / 127.0f, 1e-8f);
    for (int j = tid; j < cols; j += 256) {
        float q = rintf(p[j] / scale);
        q = fminf(fmaxf(q, -127.0f), 127.0f);
        float v = q * scale;
        u16 h = f2bf(v);
        ph[j] = h;
        pl[j] = f2bf(v - bf2f(h));
    }
}

// ---------------- RoPE in place, x:(S, nh, 128), cos/sin:(S,128) -----------
__global__ void rope_kernel(float* __restrict__ x, const float* __restrict__ c,
                            const float* __restrict__ s, int nh) {
    int idx = blockIdx.x * 256 + threadIdx.x;
    int d = idx & 63;
    int t = idx >> 6;
    int h = t % nh;
    int sq = t / nh;
    size_t base = ((size_t)sq * nh + h) * 128;
    float a = x[base + d], b = x[base + d + 64];
    float c1 = c[sq * 128 + d], s1 = s[sq * 128 + d];
    float c2 = c[sq * 128 + d + 64], s2 = s[sq * 128 + d + 64];
    x[base + d] = a * c1 - b * s1;
    x[base + d + 64] = b * c2 + a * s2;
}

// ===========================================================================
extern "C" void kernel_launch(void* const* d_in, const int* in_sizes, int n_in,
                              void* d_out, int out_size, void* d_ws, size_t ws_size,
                              hipStream_t stream) {
    const float* hidden = (const float*)d_in[0];
    const float* cosp   = (const float*)d_in[1];
    const float* sinp   = (const float*)d_in[2];
    const float* Wq     = (const float*)d_in[3];
    const float* Wk     = (const float*)d_in[4];
    const float* Wv     = (const float*)d_in[5];
    const float* Wo     = (const float*)d_in[6];
    const float* Lp     = (const float*)d_in[7];
    const float* Rp     = (const float*)d_in[8];
    const float* diag   = (const float*)d_in[9];
    const float* Tkp    = (const float*)d_in[10];
    const float* Tvp    = (const float*)d_in[11];
    float* out = (float*)d_out;

    const size_t MiB = 1ull << 20;
    char* W = (char*)d_ws;
    auto F = [&](size_t mb) { return (float*)(W + mb * MiB); };
    auto U = [&](size_t mb) { return (u16*)(W + mb * MiB); };
    const long HP = 4194304, HP2 = 2097152;

    // small scratch in d_out (final GEMM overwrites all of d_out)
    float* dsc   = (float*)d_out;
    float* invL  = dsc;
    float* invR  = dsc + 1024;
    float* invTk = dsc + 5120;
    float* invTv = dsc + 21504;
    u16* sm = (u16*)(dsc + 37888);
    u16* invTk_sh = sm;              u16* invTk_sl = sm + 16384;
    u16* TkT_sh   = sm + 2 * 16384;  u16* TkT_sl   = sm + 3 * 16384;
    u16* invTvT_sh= sm + 4 * 16384;  u16* invTvT_sl= sm + 5 * 16384;
    u16* TvT_sh   = sm + 6 * 16384;  u16* TvT_sl   = sm + 7 * 16384;

    auto gemm = [&](dim3 grid,
                    const u16* Ah, const u16* Al, int lda, long aZ, int aDiv,
                    const u16* Bh, const u16* Bl, int ldb, long bZ, int bDiv,
                    float* C, int ldc, long cZ, int cDiv, int K, float alpha) {
        gemm_kernel<<<grid, 256, 0, stream>>>(Ah, Al, lda, aZ, aDiv,
            Bh, Bl, ldb, bZ, bDiv, C, ldc, cZ, cDiv, K, alpha);
    };

    // ---- P0: inverses + small splits ----
    gj4_kernel<<<4, 1024, 0, stream>>>(Lp, invL, Rp, invR, Tkp, invTk, Tvp, invTv);
    split_kernel<<<16, 256, 0, stream>>>(invTk, invTk_sh, invTk_sl, 16384);
    split_t_kernel<<<dim3(4, 4), 256, 0, stream>>>(Tkp, TkT_sh, TkT_sl, 128, 128);
    split_t_kernel<<<dim3(4, 4), 256, 0, stream>>>(invTv, invTvT_sh, invTvT_sl, 128, 128);
    split_t_kernel<<<dim3(4, 4), 256, 0, stream>>>(Tvp, TvT_sh, TvT_sl, 128, 128);

    u16* PT_s   = U(0);    // [0,16)
    u16* PINV_s = U(16);   // [16,32)
    build_PT_s_kernel<<<16384, 256, 0, stream>>>(Lp, Rp, diag, PT_s, PT_s + HP);
    build_Pinv_s_kernel<<<16384, 256, 0, stream>>>(invL, invR, diag, PINV_s, PINV_s + HP);

    // ---- P1: weight prep ----
    u16* tmp_s = U(32);   // [32,48)
    float* tmpf = F(48);  // [48,64)
    u16* WQ_s = U(64);    // [64,80)
    u16* WK_s = U(80);    // [80,88)
    u16* WV_s = U(88);    // [88,96)

    split_kernel<<<4096, 256, 0, stream>>>(Wq, tmp_s, tmp_s + HP, 4194304);
    gemm(dim3(16, 16, 1), tmp_s, tmp_s + HP, 2048, 0, 0,
         PINV_s, PINV_s + HP, 2048, 0, 0, tmpf, 2048, 0, 0, 2048, 1.0f);
    rowquant_split_kernel<<<2048, 256, 0, stream>>>(tmpf, WQ_s, WQ_s + HP, 2048);

    split_kernel<<<2048, 256, 0, stream>>>(Wk, tmp_s, tmp_s + HP2, 2097152);
    gemm(dim3(16, 8, 1), tmp_s, tmp_s + HP2, 2048, 0, 0,
         PINV_s, PINV_s + HP, 2048, 0, 0, tmpf, 2048, 0, 0, 2048, 1.0f);
    rowquant_split_kernel<<<1024, 256, 0, stream>>>(tmpf, WK_s, WK_s + HP2, 2048);

    split_kernel<<<2048, 256, 0, stream>>>(Wv, tmp_s, tmp_s + HP2, 2097152);
    gemm(dim3(16, 8, 1), tmp_s, tmp_s + HP2, 2048, 0, 0,
         PINV_s, PINV_s + HP, 2048, 0, 0, tmpf, 2048, 0, 0, 2048, 1.0f);
    u16* WVPt_s = U(56);  // [56,64) (tmpf only occupies [48,56) here)
    split_t_kernel<<<dim3(64, 32), 256, 0, stream>>>(tmpf, WVPt_s, WVPt_s + HP2, 1024, 2048);
    float* WVf = F(32);   // [32,40) over tmp_s (dead)
    gemm(dim3(16, 1, 8), TvT_sh, TvT_sl, 128, 0, 0,
         WVPt_s, WVPt_s + HP2, 1024, 128, 0, WVf, 2048, (long)128 * 2048, 0, 128, 1.0f);
    rowquant_split_kernel<<<1024, 256, 0, stream>>>(WVf, WV_s, WV_s + HP2, 2048);

    split_kernel<<<4096, 256, 0, stream>>>(hidden, tmp_s, tmp_s + HP, 4194304);
    gemm(dim3(16, 16, 1), tmp_s, tmp_s + HP, 2048, 0, 0,
         PT_s, PT_s + HP, 2048, 0, 0, tmpf, 2048, 0, 0, 2048, 1.0f);
    u16* X_s = U(0);      // [0,16) over PT_s (dead)
    rowquant_split_kernel<<<2048, 256, 0, stream>>>(tmpf, X_s, X_s + HP, 2048);

    // ---- P2: projections, RoPE, head transforms ----
    float* Qf  = F(16);   // [16,32) over PINV_s (dead)
    float* KBf = F(32);   // [32,40)
    float* Vf  = F(40);   // [40,48)
    gemm(dim3(16, 16, 1), X_s, X_s + HP, 2048, 0, 0,
         WQ_s, WQ_s + HP, 2048, 0, 0, Qf, 2048, 0, 0, 2048, 1.0f);
    gemm(dim3(8, 16, 1), X_s, X_s + HP, 2048, 0, 0,
         WK_s, WK_s + HP2, 2048, 0, 0, KBf, 1024, 0, 0, 2048, 1.0f);
    gemm(dim3(8, 16, 1), X_s, X_s + HP, 2048, 0, 0,
         WV_s, WV_s + HP2, 2048, 0, 0, Vf, 1024, 0, 0, 2048, 1.0f);

    rope_kernel<<<8192, 256, 0, stream>>>(Qf, cosp, sinp, 16);
    rope_kernel<<<4096, 256, 0, stream>>>(KBf, cosp, sinp, 8);

    u16* Q_s = U(0);      // [0,16) over X_s (dead)
    split_kernel<<<4096, 256, 0, stream>>>(Qf, Q_s, Q_s + HP, 4194304);
    float* q2f = F(48);   // [48,64) over tmpf (dead)
    gemm(dim3(1, 16, 16), Q_s, Q_s + HP, 2048, 128, 0,
         invTk_sh, invTk_sl, 128, 0, 0, q2f, 2048, 128, 0, 128, 1.0f);

    u16* KB_s = U(16);    // [16,24) over Qf (dead)
    split_kernel<<<2048, 256, 0, stream>>>(KBf, KB_s, KB_s + HP2, 2097152);
    float* k2f = F(24);   // [24,32)
    gemm(dim3(1, 16, 8), KB_s, KB_s + HP2, 1024, 128, 0,
         TkT_sh, TkT_sl, 128, 0, 0, k2f, 1024, 128, 0, 128, 1.0f);
    u16* k2_s = U(88);    // [88,96) over WV_s (dead)
    rowquant_split_kernel<<<16384, 256, 0, stream>>>(k2f, k2_s, k2_s + HP2, 128);

    rowquant_kernel<<<16384, 256, 0, stream>>>(Vf, 128);
    u16* vT_s = U(64);    // [64,72) over WQ_s (dead)
    split_t_kernel<<<dim3(32, 64), 256, 0, stream>>>(Vf, vT_s, vT_s + HP2, 2048, 1024);

    // ---- P3: flash attention ----
    float* of = F(32);    // [32,48) over KBf/Vf (dead)
    flash_kernel<<<dim3(16, 32), 256, 0, stream>>>(
        q2f, k2_s, k2_s + HP2, vT_s, vT_s + HP2, of);

    // ---- P4: output transform + final projection ----
    u16* o_s = U(0);      // [0,16) over Q_s (dead)
    split_kernel<<<4096, 256, 0, stream>>>(of, o_s, o_s + HP, 4194304);
    float* o2f = F(16);   // [16,32) over KB_s/k2f (dead)
    gemm(dim3(1, 16, 16), o_s, o_s + HP, 128, 262144, 0,
         invTvT_sh, invTvT_sl, 128, 0, 0, o2f, 2048, 128, 0, 128, 1.0f);
    u16* o2q_s = U(32);   // [32,48) over of (dead)
    rowquant_split_kernel<<<2048, 256, 0, stream>>>(o2f, o2q_s, o2q_s + HP, 2048);
    u16* Wo_s = U(48);    // [48,64) over q2f (dead)
    rowquant_split_kernel<<<2048, 256, 0, stream>>>(Wo, Wo_s, Wo_s + HP, 2048);
    gemm(dim3(16, 16, 1), o2q_s, o2q_s + HP, 2048, 0, 0,
         Wo_s, Wo_s + HP, 2048, 0, 0, out, 2048, 0, 0, 2048, 1.0f);

    (void)in_sizes; (void)n_in; (void)out_size; (void)ws_size;
}

// Round 5
// 968.456 us; speedup vs baseline: 10.0641x; 1.2260x over previous
//
#include <hip/hip_runtime.h>
#include <math.h>

typedef unsigned short u16;
typedef __attribute__((ext_vector_type(8))) short bf16x8;
typedef __attribute__((ext_vector_type(4))) float f32x4;

__device__ __forceinline__ u16 f2bf(float x) {
    union { float f; unsigned int u; } c; c.f = x;
    unsigned int r = c.u + 0x7fffu + ((c.u >> 16) & 1u);
    return (u16)(r >> 16);
}
__device__ __forceinline__ float bf2f(u16 h) {
    union { unsigned int u; float f; } c; c.u = ((unsigned int)h) << 16;
    return c.f;
}
__device__ __forceinline__ bf16x8 ld16(const u16* p) {
    bf16x8 r;
    ((uint2*)&r)[0] = *(const uint2*)p;
    ((uint2*)&r)[1] = *(const uint2*)(p + 4);
    return r;
}
__device__ __forceinline__ void st8(u16* dst, uint4 r) {
    *(uint2*)dst = make_uint2(r.x, r.y);
    *(uint2*)(dst + 4) = make_uint2(r.z, r.w);
}

// ---------------- register-resident Gauss-Jordan, 4 matrices ---------------
__global__ __launch_bounds__(1024) void gj4_kernel(
    const float* __restrict__ A0, float* __restrict__ I0,
    const float* __restrict__ A1, float* __restrict__ I1,
    const float* __restrict__ A2, float* __restrict__ I2,
    const float* __restrict__ A3, float* __restrict__ I3) {
    __shared__ float rowbuf[2][128];
    __shared__ float colbuf[2][128];
    const float* A; float* out; int N;
    switch (blockIdx.x) {
        case 0:  A = A0; out = I0; N = 32;  break;
        case 1:  A = A1; out = I1; N = 64;  break;
        case 2:  A = A2; out = I2; N = 128; break;
        default: A = A3; out = I3; N = 128; break;
    }
    const int tid = threadIdx.x;
    const int i = tid >> 3, c0 = (tid & 7) * 16;
    float r[16];
#pragma unroll
    for (int e = 0; e < 16; ++e) {
        int j = c0 + e;
        r[e] = (i < N && j < N) ? A[i * N + j] : (i == j ? 1.0f : 0.0f);
    }
    if ((tid & 7) == 0) colbuf[0][i] = r[0];
    __syncthreads();
    for (int k = 0; k < 128; ++k) {
        int pb = k & 1;
        if (i == k) {
            float ip = 1.0f / colbuf[pb][k];
#pragma unroll
            for (int e = 0; e < 16; ++e)
                rowbuf[pb][c0 + e] = (c0 + e == k) ? ip : r[e] * ip;
        }
        __syncthreads();
        float ci = colbuf[pb][i];
        float rb[16];
#pragma unroll
        for (int e = 0; e < 16; ++e) rb[e] = rowbuf[pb][c0 + e];
        if (i == k) {
#pragma unroll
            for (int e = 0; e < 16; ++e) r[e] = rb[e];
        } else {
#pragma unroll
            for (int e = 0; e < 16; ++e) {
                float v = (c0 + e == k) ? 0.0f : r[e];
                r[e] = fmaf(-ci, rb[e], v);
            }
        }
        if (k + 1 < 128 && ((k + 1) >> 4) == (tid & 7))
            colbuf[(k + 1) & 1][i] = r[(k + 1) & 15];
        __syncthreads();
    }
    if (i < N)
#pragma unroll
        for (int e = 0; e < 16; ++e) {
            int j = c0 + e;
            if (j < N) out[i * N + j] = r[e];
        }
}

// ---------------- split fp32 -> (hi, lo) bf16 planes -----------------------
__global__ void split_kernel(const float* __restrict__ in, u16* __restrict__ hi,
                             u16* __restrict__ lo, int n) {
    int idx = (blockIdx.x * 256 + threadIdx.x) * 4;
    if (idx >= n) return;
    float4 v = *(const float4*)(in + idx);
    ushort4 h, l;
    h.x = f2bf(v.x); l.x = f2bf(v.x - bf2f(h.x));
    h.y = f2bf(v.y); l.y = f2bf(v.y - bf2f(h.y));
    h.z = f2bf(v.z); l.z = f2bf(v.z - bf2f(h.z));
    h.w = f2bf(v.w); l.w = f2bf(v.w - bf2f(h.w));
    *(ushort4*)(hi + idx) = h;
    *(ushort4*)(lo + idx) = l;
}

// ---------------- transpose + split fp32: out[c][r] = in[r][c] -------------
__global__ void split_t_kernel(const float* __restrict__ in, u16* __restrict__ hi,
                               u16* __restrict__ lo, int rows, int cols) {
    __shared__ float t[32][33];
    int bx = blockIdx.x, by = blockIdx.y;
    int lx = threadIdx.x & 31, ly = threadIdx.x >> 5;
    for (int r = ly; r < 32; r += 8)
        t[r][lx] = in[(size_t)(by * 32 + r) * cols + bx * 32 + lx];
    __syncthreads();
    for (int r = ly; r < 32; r += 8) {
        float v = t[lx][r];
        size_t o = (size_t)(bx * 32 + r) * rows + by * 32 + lx;
        u16 h = f2bf(v);
        hi[o] = h;
        lo[o] = f2bf(v - bf2f(h));
    }
}

// ---------------- u16 transpose: out[c][r] = in[r][c] ----------------------
__global__ void trans16_kernel(const u16* __restrict__ in, u16* __restrict__ out,
                               int rows, int cols) {
    __shared__ u16 t[64][72];
    int bx = blockIdx.x, by = blockIdx.y;
    int tid = threadIdx.x;
#pragma unroll
    for (int it = 0; it < 2; ++it) {
        int ii = tid + it * 256;
        int r = ii >> 3, c8 = (ii & 7) * 8;
        uint4 v = *(const uint4*)(in + (size_t)(by * 64 + r) * cols + bx * 64 + c8);
        st8(&t[r][c8], v);
    }
    __syncthreads();
#pragma unroll
    for (int it = 0; it < 2; ++it) {
        int ii = tid + it * 256;
        int r = ii >> 3, c8 = (ii & 7) * 8;
        u16 tmp[8];
#pragma unroll
        for (int e = 0; e < 8; ++e) tmp[e] = t[c8 + e][r];
        uint4 v;
        v.x = tmp[0] | ((unsigned)tmp[1] << 16); v.y = tmp[2] | ((unsigned)tmp[3] << 16);
        v.z = tmp[4] | ((unsigned)tmp[5] << 16); v.w = tmp[6] | ((unsigned)tmp[7] << 16);
        *(uint4*)(out + (size_t)(bx * 64 + r) * rows + by * 64 + c8) = v;
    }
}

// ---------------- build P^T and Pinv directly as split planes --------------
__global__ void build_PT_s_kernel(const float* __restrict__ L, const float* __restrict__ R,
                                  const float* __restrict__ dg, u16* __restrict__ hi,
                                  u16* __restrict__ lo) {
    int idx = blockIdx.x * 256 + threadIdx.x;
    int j = idx >> 11, i = idx & 2047;
    float v = dg[i] * L[(i >> 6) * 32 + (j >> 6)] * R[((i & 63) << 6) + (j & 63)];
    u16 h = f2bf(v); hi[idx] = h; lo[idx] = f2bf(v - bf2f(h));
}
__global__ void build_Pinv_s_kernel(const float* __restrict__ invL, const float* __restrict__ invR,
                                    const float* __restrict__ dg, u16* __restrict__ hi,
                                    u16* __restrict__ lo) {
    int idx = blockIdx.x * 256 + threadIdx.x;
    int i = idx >> 11, j = idx & 2047;
    float v = invL[(i >> 6) * 32 + (j >> 6)] * invR[((i & 63) << 6) + (j & 63)] / dg[j];
    u16 h = f2bf(v); hi[idx] = h; lo[idx] = f2bf(v - bf2f(h));
}

// ---------------- split-bf16 MFMA GEMM: C = alpha * A * B^T (fp32 out) -----
__global__ __launch_bounds__(256) void gemm_kernel(
    const u16* __restrict__ Ah, const u16* __restrict__ Al, int lda, long aZ, int aDiv,
    const u16* __restrict__ Bh, const u16* __restrict__ Bl, int ldb, long bZ, int bDiv,
    float* __restrict__ C, int ldc, long cZ, int cDiv, int K, float alpha) {
    const int m0 = blockIdx.y * 128, n0 = blockIdx.x * 128;
    const int z = blockIdx.z;
    {
        long ao = (long)(z >> aDiv) * aZ;
        long bo = (long)(z >> bDiv) * bZ;
        Ah += ao; Al += ao; Bh += bo; Bl += bo;
    }
    __shared__ u16 Ash[2][2][128][36];
    __shared__ u16 Bsh[2][2][128][36];

    const int tid = threadIdx.x, lane = tid & 63, wave = tid >> 6;
    const int wr = wave >> 1, wc = wave & 1;
    const int fr = lane & 15, fg8 = (lane >> 4) * 8;
    const int srow = tid >> 2, cc8 = (tid & 3) * 8;

    f32x4 acc[4][4];
#pragma unroll
    for (int m = 0; m < 4; ++m)
#pragma unroll
        for (int n = 0; n < 4; ++n) acc[m][n] = (f32x4)0.0f;

    uint4 rah0, rah1, ral0, ral1, rbh0, rbh1, rbl0, rbl1;
    const size_t aoff0 = (size_t)(m0 + srow) * lda + cc8;
    const size_t aoff1 = aoff0 + (size_t)64 * lda;
    const size_t boff0 = (size_t)(n0 + srow) * ldb + cc8;
    const size_t boff1 = boff0 + (size_t)64 * ldb;

#define G_LOAD(k0) { \
    rah0 = *(const uint4*)(Ah + aoff0 + (k0)); rah1 = *(const uint4*)(Ah + aoff1 + (k0)); \
    ral0 = *(const uint4*)(Al + aoff0 + (k0)); ral1 = *(const uint4*)(Al + aoff1 + (k0)); \
    rbh0 = *(const uint4*)(Bh + boff0 + (k0)); rbh1 = *(const uint4*)(Bh + boff1 + (k0)); \
    rbl0 = *(const uint4*)(Bl + boff0 + (k0)); rbl1 = *(const uint4*)(Bl + boff1 + (k0)); }
#define G_STORE(b) { \
    st8(&Ash[b][0][srow][cc8], rah0); st8(&Ash[b][0][srow + 64][cc8], rah1); \
    st8(&Ash[b][1][srow][cc8], ral0); st8(&Ash[b][1][srow + 64][cc8], ral1); \
    st8(&Bsh[b][0][srow][cc8], rbh0); st8(&Bsh[b][0][srow + 64][cc8], rbh1); \
    st8(&Bsh[b][1][srow][cc8], rbl0); st8(&Bsh[b][1][srow + 64][cc8], rbl1); }

    const int nk = K >> 5;
    G_LOAD(0);
    G_STORE(0);
    __syncthreads();
    int cur = 0;
    for (int ik = 0; ik < nk; ++ik) {
        if (ik + 1 < nk) G_LOAD((ik + 1) << 5);
        bf16x8 bh[4], bl[4];
#pragma unroll
        for (int n = 0; n < 4; ++n) {
            bh[n] = ld16(&Bsh[cur][0][wc * 64 + n * 16 + fr][fg8]);
            bl[n] = ld16(&Bsh[cur][1][wc * 64 + n * 16 + fr][fg8]);
        }
#pragma unroll
        for (int m = 0; m < 4; ++m) {
            bf16x8 ah = ld16(&Ash[cur][0][wr * 64 + m * 16 + fr][fg8]);
            bf16x8 al = ld16(&Ash[cur][1][wr * 64 + m * 16 + fr][fg8]);
#pragma unroll
            for (int n = 0; n < 4; ++n) {
                acc[m][n] = __builtin_amdgcn_mfma_f32_16x16x32_bf16(ah, bh[n], acc[m][n], 0, 0, 0);
                acc[m][n] = __builtin_amdgcn_mfma_f32_16x16x32_bf16(ah, bl[n], acc[m][n], 0, 0, 0);
                acc[m][n] = __builtin_amdgcn_mfma_f32_16x16x32_bf16(al, bh[n], acc[m][n], 0, 0, 0);
            }
        }
        if (ik + 1 < nk) G_STORE(cur ^ 1);
        __syncthreads();
        cur ^= 1;
    }
    const long co = (long)(z >> cDiv) * cZ;
#pragma unroll
    for (int m = 0; m < 4; ++m) {
        int row_b = m0 + wr * 64 + m * 16 + (fg8 >> 1);
#pragma unroll
        for (int n = 0; n < 4; ++n) {
            int col = n0 + wc * 64 + n * 16 + fr;
#pragma unroll
            for (int j = 0; j < 4; ++j)
                C[co + (long)(row_b + j) * ldc + col] = alpha * acc[m][n][j];
        }
    }
#undef G_LOAD
#undef G_STORE
}

// ---------------- int-bf16 MFMA GEMM: C[m,n] = sa[m]*sb[n]*sum A*B^T -------
// A,B hold exact small integers in bf16; single-plane, exact.
__global__ __launch_bounds__(256) void gemm_int_kernel(
    const u16* __restrict__ A, int lda, const float* __restrict__ sa,
    const u16* __restrict__ B, int ldb, const float* __restrict__ sb,
    float* __restrict__ C, int ldc, int K) {
    const int m0 = blockIdx.y * 128, n0 = blockIdx.x * 128;
    __shared__ u16 Ash[2][128][36];
    __shared__ u16 Bsh[2][128][36];
    const int tid = threadIdx.x, lane = tid & 63, wave = tid >> 6;
    const int wr = wave >> 1, wc = wave & 1;
    const int fr = lane & 15, fg8 = (lane >> 4) * 8;
    const int srow = tid >> 2, cc8 = (tid & 3) * 8;
    f32x4 acc[4][4];
#pragma unroll
    for (int m = 0; m < 4; ++m)
#pragma unroll
        for (int n = 0; n < 4; ++n) acc[m][n] = (f32x4)0.0f;

    uint4 ra0, ra1, rb0, rb1;
    const size_t aoff0 = (size_t)(m0 + srow) * lda + cc8;
    const size_t aoff1 = aoff0 + (size_t)64 * lda;
    const size_t boff0 = (size_t)(n0 + srow) * ldb + cc8;
    const size_t boff1 = boff0 + (size_t)64 * ldb;
#define GI_LOAD(k0) { \
    ra0 = *(const uint4*)(A + aoff0 + (k0)); ra1 = *(const uint4*)(A + aoff1 + (k0)); \
    rb0 = *(const uint4*)(B + boff0 + (k0)); rb1 = *(const uint4*)(B + boff1 + (k0)); }
#define GI_STORE(b) { \
    st8(&Ash[b][srow][cc8], ra0); st8(&Ash[b][srow + 64][cc8], ra1); \
    st8(&Bsh[b][srow][cc8], rb0); st8(&Bsh[b][srow + 64][cc8], rb1); }
    const int nk = K >> 5;
    GI_LOAD(0);
    GI_STORE(0);
    __syncthreads();
    int cur = 0;
    for (int ik = 0; ik < nk; ++ik) {
        if (ik + 1 < nk) GI_LOAD((ik + 1) << 5);
        bf16x8 bfr[4];
#pragma unroll
        for (int n = 0; n < 4; ++n)
            bfr[n] = ld16(&Bsh[cur][wc * 64 + n * 16 + fr][fg8]);
#pragma unroll
        for (int m = 0; m < 4; ++m) {
            bf16x8 ah = ld16(&Ash[cur][wr * 64 + m * 16 + fr][fg8]);
#pragma unroll
            for (int n = 0; n < 4; ++n)
                acc[m][n] = __builtin_amdgcn_mfma_f32_16x16x32_bf16(ah, bfr[n], acc[m][n], 0, 0, 0);
        }
        if (ik + 1 < nk) GI_STORE(cur ^ 1);
        __syncthreads();
        cur ^= 1;
    }
#pragma unroll
    for (int m = 0; m < 4; ++m) {
        int row_b = m0 + wr * 64 + m * 16 + (fg8 >> 1);
#pragma unroll
        for (int n = 0; n < 4; ++n) {
            int col = n0 + wc * 64 + n * 16 + fr;
            float sc = sb[col];
#pragma unroll
            for (int j = 0; j < 4; ++j)
                C[(long)(row_b + j) * ldc + col] = acc[m][n][j] * sa[row_b + j] * sc;
        }
    }
#undef GI_LOAD
#undef GI_STORE
}

// ---------------- per-row fake_quant -> int-valued bf16 + scale ------------
__global__ void rowquant_int_kernel(const float* __restrict__ x, u16* __restrict__ qi,
                                    float* __restrict__ sc, int cols) {
    __shared__ float red[256];
    int row = blockIdx.x, tid = threadIdx.x;
    const float* p = x + (size_t)row * cols;
    u16* q = qi + (size_t)row * cols;
    float m = 0.0f;
    for (int j = tid; j < cols; j += 256) m = fmaxf(m, fabsf(p[j]));
    red[tid] = m; __syncthreads();
    for (int s = 128; s > 0; s >>= 1) {
        if (tid < s) red[tid] = fmaxf(red[tid], red[tid + s]);
        __syncthreads();
    }
    float scale = fmaxf(red[0] / 127.0f, 1e-8f);
    if (tid == 0) sc[row] = scale;
    for (int j = tid; j < cols; j += 256) {
        float v = rintf(p[j] / scale);
        v = fminf(fmaxf(v, -127.0f), 127.0f);
        q[j] = f2bf(v);   // integer <= 127: exact in bf16
    }
}

// ---------------- RoPE in place, x:(S, nh, 128), cos/sin:(S,128) -----------
__global__ void rope_kernel(float* __restrict__ x, const float* __restrict__ c,
                            const float* __restrict__ s, int nh) {
    int idx = blockIdx.x * 256 + threadIdx.x;
    int d = idx & 63;
    int t = idx >> 6;
    int h = t % nh;
    int sq = t / nh;
    size_t base = ((size_t)sq * nh + h) * 128;
    float a = x[base + d], b = x[base + d + 64];
    float c1 = c[sq * 128 + d], s1 = s[sq * 128 + d];
    float c2 = c[sq * 128 + d + 64], s2 = s[sq * 128 + d + 64];
    x[base + d] = a * c1 - b * s1;
    x[base + d + 64] = b * c2 + a * s2;
}

// ---------------- flash attention v2 (int K/V, single plane) ---------------
// grid (16 heads, 32 q-tiles, heavy-first). 256 thr = 4 waves, wave: 16 rows.
// q2f fp32 [2048][2048]; k2i int-bf16 [2048][1024], ksc[16384] (s*8+g);
// vTi int-bf16 [1024][2048], vsc[16384] (s*8+g); o fp32 [16][2048][128].
__global__ __launch_bounds__(256) void flash_kernel(
    const float* __restrict__ q2f,
    const u16* __restrict__ k2i, const float* __restrict__ ksc,
    const u16* __restrict__ vTi, const float* __restrict__ vsc,
    float* __restrict__ o) {
    const int h = blockIdx.x, qt = 31 - blockIdx.y, g = h >> 1;
    __shared__ u16 Ksh[2][64 * 128];
    __shared__ u16 Vsh[2][128 * 64];
    __shared__ u16 Psh[4][16 * 64];
    __shared__ float Kss[2][64];
    __shared__ float Vss[2][64];

    const int tid = threadIdx.x, lane = tid & 63, w = tid >> 6;
    const int lc = lane & 15, lg = lane >> 4;
    const float scale = 0.08838834764831845f;

    // Q fragments (scale folded), 2-plane split in registers
    bf16x8 qh[4], ql[4];
    {
        int s = qt * 64 + w * 16 + lc;
        const float* qp = q2f + (size_t)s * 2048 + h * 128 + lg * 8;
#pragma unroll
        for (int kk = 0; kk < 4; ++kk) {
            float4 v0 = *(const float4*)(qp + kk * 32);
            float4 v1 = *(const float4*)(qp + kk * 32 + 4);
            float vv[8] = {v0.x, v0.y, v0.z, v0.w, v1.x, v1.y, v1.z, v1.w};
#pragma unroll
            for (int e = 0; e < 8; ++e) {
                float x = vv[e] * scale;
                u16 hh = f2bf(x);
                qh[kk][e] = (short)hh;
                ql[kk][e] = (short)f2bf(x - bf2f(hh));
            }
        }
    }

    f32x4 acc_o[8];
#pragma unroll
    for (int nn = 0; nn < 8; ++nn) acc_o[nn] = (f32x4)0.0f;
    float mj[4] = {-1e30f, -1e30f, -1e30f, -1e30f};
    float lj[4] = {0.0f, 0.0f, 0.0f, 0.0f};

#define STAGE(t, b) { \
    const int j0_ = (t) * 64; \
    for (int ii = tid; ii < 1024; ii += 256) { \
        int r = ii >> 4, c4 = ii & 15; \
        *(uint4*)(&Ksh[b][r * 128 + ((c4 ^ (r & 7)) << 3)]) = \
            *(const uint4*)(k2i + (size_t)(j0_ + r) * 1024 + g * 128 + c4 * 8); \
    } \
    for (int ii = tid; ii < 1024; ii += 256) { \
        int d = ii >> 3, c4 = ii & 7; \
        *(uint4*)(&Vsh[b][d * 64 + ((c4 ^ (d & 7)) << 3)]) = \
            *(const uint4*)(vTi + (size_t)(g * 128 + d) * 2048 + j0_ + c4 * 8); \
    } \
    if (tid < 64) Kss[b][tid] = ksc[(j0_ + tid) * 8 + g]; \
    else if (tid < 128) Vss[b][tid - 64] = vsc[(j0_ + tid - 64) * 8 + g]; }

    STAGE(0, 0);
    __syncthreads();
    for (int t = 0; t <= qt; ++t) {
        const int cur = t & 1;
        if (t < qt) STAGE(t + 1, cur ^ 1);

        // ---- QK^T: (qh+ql) x exact-int K, then column scale ----
        f32x4 accs[4];
#pragma unroll
        for (int n = 0; n < 4; ++n) accs[n] = (f32x4)0.0f;
        const int nlim = (t == qt) ? w : 3;
        for (int n = 0; n <= nlim; ++n) {
#pragma unroll
            for (int kk = 0; kk < 4; ++kk) {
                int roff = (n * 16 + lc) * 128 + (((kk * 4 + lg) ^ (lc & 7)) << 3);
                bf16x8 kf = ld16(&Ksh[cur][roff]);
                accs[n] = __builtin_amdgcn_mfma_f32_16x16x32_bf16(qh[kk], kf, accs[n], 0, 0, 0);
                accs[n] = __builtin_amdgcn_mfma_f32_16x16x32_bf16(ql[kk], kf, accs[n], 0, 0, 0);
            }
            float s_ = Kss[cur][n * 16 + lc];
#pragma unroll
            for (int j = 0; j < 4; ++j) accs[n][j] *= s_;
        }
        if (t == qt) {
#pragma unroll
            for (int j = 0; j < 4; ++j)
                if (lc > lg * 4 + j) accs[w][j] = -1e30f;
        }

        // ---- online softmax ----
        float sf[4], rs[4];
#pragma unroll
        for (int j = 0; j < 4; ++j) {
            float v = accs[0][j];
            for (int n = 1; n <= nlim; ++n) v = fmaxf(v, accs[n][j]);
            v = fmaxf(v, __shfl_xor(v, 1));
            v = fmaxf(v, __shfl_xor(v, 2));
            v = fmaxf(v, __shfl_xor(v, 4));
            v = fmaxf(v, __shfl_xor(v, 8));
            float mn = fmaxf(mj[j], v);
            sf[j] = __expf(mj[j] - mn);
            mj[j] = mn;
            rs[j] = 0.0f;
        }
        for (int n = 0; n <= nlim; ++n)
#pragma unroll
            for (int j = 0; j < 4; ++j) {
                float p = __expf(accs[n][j] - mj[j]);
                accs[n][j] = p;
                rs[j] += p;
            }
#pragma unroll
        for (int j = 0; j < 4; ++j) {
            float v = rs[j];
            v += __shfl_xor(v, 1);
            v += __shfl_xor(v, 2);
            v += __shfl_xor(v, 4);
            v += __shfl_xor(v, 8);
            lj[j] = lj[j] * sf[j] + v;
        }
#pragma unroll
        for (int nn = 0; nn < 8; ++nn)
#pragma unroll
            for (int j = 0; j < 4; ++j) acc_o[nn][j] *= sf[j];

        // ---- P' = P * vscale(col) -> wave-private LDS (hi bf16) ----
#pragma unroll
        for (int n = 0; n < 4; ++n)
#pragma unroll
            for (int j = 0; j < 4; ++j) {
                int rr = lg * 4 + j, c = n * 16 + lc;
                u16 val = (n <= nlim) ? f2bf(accs[n][j] * Vss[cur][c]) : (u16)0;
                Psh[w][rr * 64 + (((c >> 3) ^ (rr & 7)) << 3) + (c & 7)] = val;
            }
        bf16x8 pf[2];
#pragma unroll
        for (int kk = 0; kk < 2; ++kk)
            pf[kk] = ld16(&Psh[w][lc * 64 + (((kk * 4 + lg) ^ (lc & 7)) << 3)]);

        // ---- PV: P' x exact-int V ----
#pragma unroll
        for (int nn = 0; nn < 8; ++nn) {
#pragma unroll
            for (int kk = 0; kk < 2; ++kk) {
                int voff = (nn * 16 + lc) * 64 + (((kk * 4 + lg) ^ (lc & 7)) << 3);
                bf16x8 vf = ld16(&Vsh[cur][voff]);
                acc_o[nn] = __builtin_amdgcn_mfma_f32_16x16x32_bf16(pf[kk], vf, acc_o[nn], 0, 0, 0);
            }
        }
        __syncthreads();
    }
#undef STAGE

    // ---- epilogue ----
    float linv[4];
#pragma unroll
    for (int j = 0; j < 4; ++j) linv[j] = 1.0f / lj[j];
#pragma unroll
    for (int nn = 0; nn < 8; ++nn)
#pragma unroll
        for (int j = 0; j < 4; ++j) {
            int s = qt * 64 + w * 16 + lg * 4 + j;
            o[((size_t)h * 2048 + s) * 128 + nn * 16 + lc] = acc_o[nn][j] * linv[j];
        }
}

// ===========================================================================
extern "C" void kernel_launch(void* const* d_in, const int* in_sizes, int n_in,
                              void* d_out, int out_size, void* d_ws, size_t ws_size,
                              hipStream_t stream) {
    const float* hidden = (const float*)d_in[0];
    const float* cosp   = (const float*)d_in[1];
    const float* sinp   = (const float*)d_in[2];
    const float* Wq     = (const float*)d_in[3];
    const float* Wk     = (const float*)d_in[4];
    const float* Wv     = (const float*)d_in[5];
    const float* Wo     = (const float*)d_in[6];
    const float* Lp     = (const float*)d_in[7];
    const float* Rp     = (const float*)d_in[8];
    const float* diag   = (const float*)d_in[9];
    const float* Tkp    = (const float*)d_in[10];
    const float* Tvp    = (const float*)d_in[11];
    float* out = (float*)d_out;

    const size_t MiB = 1ull << 20;
    char* W = (char*)d_ws;
    auto F = [&](size_t mb) { return (float*)(W + mb * MiB); };
    auto U = [&](size_t mb) { return (u16*)(W + mb * MiB); };
    const long HP = 4194304, HP2 = 2097152;

    // small scratch in d_out (final GEMM overwrites all of d_out)
    float* dsc   = (float*)d_out;
    float* invL  = dsc;
    float* invR  = dsc + 1024;
    float* invTk = dsc + 5120;
    float* invTv = dsc + 21504;
    u16* sm = (u16*)(dsc + 37888);
    u16* invTk_sh = sm;              u16* invTk_sl = sm + 16384;
    u16* TkT_sh   = sm + 2 * 16384;  u16* TkT_sl   = sm + 3 * 16384;
    u16* invTvT_sh= sm + 4 * 16384;  u16* invTvT_sl= sm + 5 * 16384;
    u16* TvT_sh   = sm + 6 * 16384;  u16* TvT_sl   = sm + 7 * 16384;

    auto gemm = [&](dim3 grid,
                    const u16* Ah, const u16* Al, int lda, long aZ, int aDiv,
                    const u16* Bh, const u16* Bl, int ldb, long bZ, int bDiv,
                    float* C, int ldc, long cZ, int cDiv, int K, float alpha) {
        gemm_kernel<<<grid, 256, 0, stream>>>(Ah, Al, lda, aZ, aDiv,
            Bh, Bl, ldb, bZ, bDiv, C, ldc, cZ, cDiv, K, alpha);
    };

    // scales area: F(88)
    float* xs  = F(88);
    float* wqs = xs + 2048;
    float* wks = wqs + 2048;
    float* wvs = wks + 1024;
    float* k2s = wvs + 1024;        // 16384
    float* vs  = k2s + 16384;       // 16384
    float* o2s = vs + 16384;
    float* wos = o2s + 2048;

    // ---- P0: inverses + small splits ----
    gj4_kernel<<<4, 1024, 0, stream>>>(Lp, invL, Rp, invR, Tkp, invTk, Tvp, invTv);
    split_kernel<<<16, 256, 0, stream>>>(invTk, invTk_sh, invTk_sl, 16384);
    split_t_kernel<<<dim3(4, 4), 256, 0, stream>>>(Tkp, TkT_sh, TkT_sl, 128, 128);
    split_t_kernel<<<dim3(4, 4), 256, 0, stream>>>(invTv, invTvT_sh, invTvT_sl, 128, 128);
    split_t_kernel<<<dim3(4, 4), 256, 0, stream>>>(Tvp, TvT_sh, TvT_sl, 128, 128);

    u16* PT_s   = U(0);    // [0,16)
    u16* PINV_s = U(16);   // [16,32)
    build_PT_s_kernel<<<16384, 256, 0, stream>>>(Lp, Rp, diag, PT_s, PT_s + HP);
    build_Pinv_s_kernel<<<16384, 256, 0, stream>>>(invL, invR, diag, PINV_s, PINV_s + HP);

    // ---- P1: weight prep -> int-bf16 + scales ----
    u16* tmp_s = U(32);   // [32,48)
    float* tmpf = F(48);  // [48,64)
    u16* WQi = U(64);     // [64,72)
    u16* WKi = U(72);     // [72,76)
    u16* WVi = U(76);     // [76,80)
    u16* Xi  = U(80);     // [80,88)

    split_kernel<<<4096, 256, 0, stream>>>(Wq, tmp_s, tmp_s + HP, 4194304);
    gemm(dim3(16, 16, 1), tmp_s, tmp_s + HP, 2048, 0, 0,
         PINV_s, PINV_s + HP, 2048, 0, 0, tmpf, 2048, 0, 0, 2048, 1.0f);
    rowquant_int_kernel<<<2048, 256, 0, stream>>>(tmpf, WQi, wqs, 2048);

    split_kernel<<<2048, 256, 0, stream>>>(Wk, tmp_s, tmp_s + HP2, 2097152);
    gemm(dim3(16, 8, 1), tmp_s, tmp_s + HP2, 2048, 0, 0,
         PINV_s, PINV_s + HP, 2048, 0, 0, tmpf, 2048, 0, 0, 2048, 1.0f);
    rowquant_int_kernel<<<1024, 256, 0, stream>>>(tmpf, WKi, wks, 2048);

    split_kernel<<<2048, 256, 0, stream>>>(Wv, tmp_s, tmp_s + HP2, 2097152);
    gemm(dim3(16, 8, 1), tmp_s, tmp_s + HP2, 2048, 0, 0,
         PINV_s, PINV_s + HP, 2048, 0, 0, tmpf, 2048, 0, 0, 2048, 1.0f);
    u16* WVPt_s = U(56);  // [56,64)
    split_t_kernel<<<dim3(64, 32), 256, 0, stream>>>(tmpf, WVPt_s, WVPt_s + HP2, 1024, 2048);
    float* WVf = F(40);   // [40,48)
    gemm(dim3(16, 1, 8), TvT_sh, TvT_sl, 128, 0, 0,
         WVPt_s, WVPt_s + HP2, 1024, 128, 0, WVf, 2048, (long)128 * 2048, 0, 128, 1.0f);
    rowquant_int_kernel<<<1024, 256, 0, stream>>>(WVf, WVi, wvs, 2048);

    split_kernel<<<4096, 256, 0, stream>>>(hidden, tmp_s, tmp_s + HP, 4194304);
    gemm(dim3(16, 16, 1), tmp_s, tmp_s + HP, 2048, 0, 0,
         PT_s, PT_s + HP, 2048, 0, 0, tmpf, 2048, 0, 0, 2048, 1.0f);
    rowquant_int_kernel<<<2048, 256, 0, stream>>>(tmpf, Xi, xs, 2048);

    // ---- P2: projections (exact int GEMMs), RoPE, head transforms ----
    float* Qf  = F(0);    // [0,16) over PT_s (dead)
    float* KBf = F(16);   // [16,24) over PINV_s (dead)
    float* Vf  = F(24);   // [24,32)
    gemm_int_kernel<<<dim3(16, 16), 256, 0, stream>>>(Xi, 2048, xs, WQi, 2048, wqs, Qf, 2048, 2048);
    gemm_int_kernel<<<dim3(8, 16), 256, 0, stream>>>(Xi, 2048, xs, WKi, 2048, wks, KBf, 1024, 2048);
    gemm_int_kernel<<<dim3(8, 16), 256, 0, stream>>>(Xi, 2048, xs, WVi, 2048, wvs, Vf, 1024, 2048);

    rope_kernel<<<8192, 256, 0, stream>>>(Qf, cosp, sinp, 16);
    rope_kernel<<<4096, 256, 0, stream>>>(KBf, cosp, sinp, 8);

    // K path: k2 = fake_quant(k @ Tk) -> int + scale
    u16* KB_s = U(32);    // [32,40) over tmp_s (dead)
    split_kernel<<<2048, 256, 0, stream>>>(KBf, KB_s, KB_s + HP2, 2097152);
    float* k2f = F(40);   // [40,48) over WVf (dead)
    gemm(dim3(1, 16, 8), KB_s, KB_s + HP2, 1024, 128, 0,
         TkT_sh, TkT_sl, 128, 0, 0, k2f, 1024, 128, 0, 128, 1.0f);
    u16* k2i = U(64);     // [64,68) over WQi (dead)
    rowquant_int_kernel<<<16384, 256, 0, stream>>>(k2f, k2i, k2s, 128);

    // V path: fake_quant(v) -> int + scale, then transpose
    u16* Vi = U(68);      // [68,72)
    rowquant_int_kernel<<<16384, 256, 0, stream>>>(Vf, Vi, vs, 128);
    u16* vTi = U(72);     // [72,76) over WKi (dead)
    trans16_kernel<<<dim3(16, 32), 256, 0, stream>>>(Vi, vTi, 2048, 1024);

    // Q path: q2 = q @ inv(Tk)^T
    u16* Q_s = U(16);     // [16,32) over KBf/Vf (dead)
    split_kernel<<<4096, 256, 0, stream>>>(Qf, Q_s, Q_s + HP, 4194304);
    float* q2f = F(32);   // [32,48) over KB_s/k2f (dead)
    gemm(dim3(1, 16, 16), Q_s, Q_s + HP, 2048, 128, 0,
         invTk_sh, invTk_sl, 128, 0, 0, q2f, 2048, 128, 0, 128, 1.0f);

    // ---- P3: flash attention ----
    float* of = F(0);     // [0,16) over Qf (dead)
    flash_kernel<<<dim3(16, 32), 256, 0, stream>>>(q2f, k2i, k2s, vTi, vs, of);

    // ---- P4: output transform + final projection ----
    u16* o_s = U(16);     // [16,32) over Q_s (dead)
    split_kernel<<<4096, 256, 0, stream>>>(of, o_s, o_s + HP, 4194304);
    float* o2f = F(48);   // [48,64) over tmpf (dead)
    gemm(dim3(1, 16, 16), o_s, o_s + HP, 128, 262144, 0,
         invTvT_sh, invTvT_sl, 128, 0, 0, o2f, 2048, 128, 0, 128, 1.0f);
    u16* o2i = U(32);     // [32,40)
    rowquant_int_kernel<<<2048, 256, 0, stream>>>(o2f, o2i, o2s, 2048);
    u16* Woi = U(40);     // [40,48)
    rowquant_int_kernel<<<2048, 256, 0, stream>>>(Wo, Woi, wos, 2048);
    gemm_int_kernel<<<dim3(16, 16), 256, 0, stream>>>(o2i, 2048, o2s, Woi, 2048, wos, out, 2048, 2048);

    (void)in_sizes; (void)n_in; (void)out_size; (void)ws_size;
}

// Round 6
// 804.121 us; speedup vs baseline: 12.1209x; 1.2044x over previous
//
#include <hip/hip_runtime.h>
#include <math.h>

typedef unsigned short u16;
typedef __attribute__((ext_vector_type(8))) short bf16x8;
typedef __attribute__((ext_vector_type(4))) float f32x4;

__device__ __forceinline__ u16 f2bf(float x) {
    union { float f; unsigned int u; } c; c.f = x;
    unsigned int r = c.u + 0x7fffu + ((c.u >> 16) & 1u);
    return (u16)(r >> 16);
}
__device__ __forceinline__ float bf2f(u16 h) {
    union { unsigned int u; float f; } c; c.u = ((unsigned int)h) << 16;
    return c.f;
}
__device__ __forceinline__ bf16x8 ld16(const u16* p) {
    bf16x8 r;
    ((uint2*)&r)[0] = *(const uint2*)p;
    ((uint2*)&r)[1] = *(const uint2*)(p + 4);
    return r;
}
__device__ __forceinline__ void st8(u16* dst, uint4 r) {
    *(uint2*)dst = make_uint2(r.x, r.y);
    *(uint2*)(dst + 4) = make_uint2(r.z, r.w);
}

// ---------------- register-resident Gauss-Jordan, 4 matrices ---------------
__global__ __launch_bounds__(1024) void gj4_kernel(
    const float* __restrict__ A0, float* __restrict__ I0,
    const float* __restrict__ A1, float* __restrict__ I1,
    const float* __restrict__ A2, float* __restrict__ I2,
    const float* __restrict__ A3, float* __restrict__ I3) {
    __shared__ float rowbuf[2][128];
    __shared__ float colbuf[2][128];
    const float* A; float* out; int N;
    switch (blockIdx.x) {
        case 0:  A = A0; out = I0; N = 32;  break;
        case 1:  A = A1; out = I1; N = 64;  break;
        case 2:  A = A2; out = I2; N = 128; break;
        default: A = A3; out = I3; N = 128; break;
    }
    const int tid = threadIdx.x;
    const int i = tid >> 3, c0 = (tid & 7) * 16;
    float r[16];
#pragma unroll
    for (int e = 0; e < 16; ++e) {
        int j = c0 + e;
        r[e] = (i < N && j < N) ? A[i * N + j] : (i == j ? 1.0f : 0.0f);
    }
    if ((tid & 7) == 0) colbuf[0][i] = r[0];
    __syncthreads();
    for (int k = 0; k < 128; ++k) {
        int pb = k & 1;
        if (i == k) {
            float ip = 1.0f / colbuf[pb][k];
#pragma unroll
            for (int e = 0; e < 16; ++e)
                rowbuf[pb][c0 + e] = (c0 + e == k) ? ip : r[e] * ip;
        }
        __syncthreads();
        float ci = colbuf[pb][i];
        float rb[16];
#pragma unroll
        for (int e = 0; e < 16; ++e) rb[e] = rowbuf[pb][c0 + e];
        if (i == k) {
#pragma unroll
            for (int e = 0; e < 16; ++e) r[e] = rb[e];
        } else {
#pragma unroll
            for (int e = 0; e < 16; ++e) {
                float v = (c0 + e == k) ? 0.0f : r[e];
                r[e] = fmaf(-ci, rb[e], v);
            }
        }
        if (k + 1 < 128 && ((k + 1) >> 4) == (tid & 7))
            colbuf[(k + 1) & 1][i] = r[(k + 1) & 15];
        __syncthreads();
    }
    if (i < N)
#pragma unroll
        for (int e = 0; e < 16; ++e) {
            int j = c0 + e;
            if (j < N) out[i * N + j] = r[e];
        }
}

// ---------------- split fp32 -> (hi, lo) bf16 planes -----------------------
__global__ void split_kernel(const float* __restrict__ in, u16* __restrict__ hi,
                             u16* __restrict__ lo, int n) {
    int idx = (blockIdx.x * 256 + threadIdx.x) * 4;
    if (idx >= n) return;
    float4 v = *(const float4*)(in + idx);
    ushort4 h, l;
    h.x = f2bf(v.x); l.x = f2bf(v.x - bf2f(h.x));
    h.y = f2bf(v.y); l.y = f2bf(v.y - bf2f(h.y));
    h.z = f2bf(v.z); l.z = f2bf(v.z - bf2f(h.z));
    h.w = f2bf(v.w); l.w = f2bf(v.w - bf2f(h.w));
    *(ushort4*)(hi + idx) = h;
    *(ushort4*)(lo + idx) = l;
}

// ---------------- transpose + split fp32: out[c][r] = in[r][c] -------------
__global__ void split_t_kernel(const float* __restrict__ in, u16* __restrict__ hi,
                               u16* __restrict__ lo, int rows, int cols) {
    __shared__ float t[32][33];
    int bx = blockIdx.x, by = blockIdx.y;
    int lx = threadIdx.x & 31, ly = threadIdx.x >> 5;
    for (int r = ly; r < 32; r += 8)
        t[r][lx] = in[(size_t)(by * 32 + r) * cols + bx * 32 + lx];
    __syncthreads();
    for (int r = ly; r < 32; r += 8) {
        float v = t[lx][r];
        size_t o = (size_t)(bx * 32 + r) * rows + by * 32 + lx;
        u16 h = f2bf(v);
        hi[o] = h;
        lo[o] = f2bf(v - bf2f(h));
    }
}

// ---------------- u16 transpose: out[c][r] = in[r][c] ----------------------
__global__ void trans16_kernel(const u16* __restrict__ in, u16* __restrict__ out,
                               int rows, int cols) {
    __shared__ u16 t[64][72];
    int bx = blockIdx.x, by = blockIdx.y;
    int tid = threadIdx.x;
#pragma unroll
    for (int it = 0; it < 2; ++it) {
        int ii = tid + it * 256;
        int r = ii >> 3, c8 = (ii & 7) * 8;
        uint4 v = *(const uint4*)(in + (size_t)(by * 64 + r) * cols + bx * 64 + c8);
        st8(&t[r][c8], v);
    }
    __syncthreads();
#pragma unroll
    for (int it = 0; it < 2; ++it) {
        int ii = tid + it * 256;
        int r = ii >> 3, c8 = (ii & 7) * 8;
        u16 tmp[8];
#pragma unroll
        for (int e = 0; e < 8; ++e) tmp[e] = t[c8 + e][r];
        uint4 v;
        v.x = tmp[0] | ((unsigned)tmp[1] << 16); v.y = tmp[2] | ((unsigned)tmp[3] << 16);
        v.z = tmp[4] | ((unsigned)tmp[5] << 16); v.w = tmp[6] | ((unsigned)tmp[7] << 16);
        *(uint4*)(out + (size_t)(bx * 64 + r) * rows + by * 64 + c8) = v;
    }
}

// ---------------- build P^T and Pinv directly as split planes --------------
__global__ void build_PT_s_kernel(const float* __restrict__ L, const float* __restrict__ R,
                                  const float* __restrict__ dg, u16* __restrict__ hi,
                                  u16* __restrict__ lo) {
    int idx = blockIdx.x * 256 + threadIdx.x;
    int j = idx >> 11, i = idx & 2047;
    float v = dg[i] * L[(i >> 6) * 32 + (j >> 6)] * R[((i & 63) << 6) + (j & 63)];
    u16 h = f2bf(v); hi[idx] = h; lo[idx] = f2bf(v - bf2f(h));
}
__global__ void build_Pinv_s_kernel(const float* __restrict__ invL, const float* __restrict__ invR,
                                    const float* __restrict__ dg, u16* __restrict__ hi,
                                    u16* __restrict__ lo) {
    int idx = blockIdx.x * 256 + threadIdx.x;
    int i = idx >> 11, j = idx & 2047;
    float v = invL[(i >> 6) * 32 + (j >> 6)] * invR[((i & 63) << 6) + (j & 63)] / dg[j];
    u16 h = f2bf(v); hi[idx] = h; lo[idx] = f2bf(v - bf2f(h));
}

// ---------------- split-bf16 MFMA GEMM: C = alpha * A * B^T (fp32 out) -----
__global__ __launch_bounds__(256) void gemm_kernel(
    const u16* __restrict__ Ah, const u16* __restrict__ Al, int lda, long aZ, int aDiv,
    const u16* __restrict__ Bh, const u16* __restrict__ Bl, int ldb, long bZ, int bDiv,
    float* __restrict__ C, int ldc, long cZ, int cDiv, int K, float alpha) {
    const int m0 = blockIdx.y * 128, n0 = blockIdx.x * 128;
    const int z = blockIdx.z;
    {
        long ao = (long)(z >> aDiv) * aZ;
        long bo = (long)(z >> bDiv) * bZ;
        Ah += ao; Al += ao; Bh += bo; Bl += bo;
    }
    __shared__ u16 Ash[2][2][128][36];
    __shared__ u16 Bsh[2][2][128][36];

    const int tid = threadIdx.x, lane = tid & 63, wave = tid >> 6;
    const int wr = wave >> 1, wc = wave & 1;
    const int fr = lane & 15, fg8 = (lane >> 4) * 8;
    const int srow = tid >> 2, cc8 = (tid & 3) * 8;

    f32x4 acc[4][4];
#pragma unroll
    for (int m = 0; m < 4; ++m)
#pragma unroll
        for (int n = 0; n < 4; ++n) acc[m][n] = (f32x4)0.0f;

    uint4 rah0, rah1, ral0, ral1, rbh0, rbh1, rbl0, rbl1;
    const size_t aoff0 = (size_t)(m0 + srow) * lda + cc8;
    const size_t aoff1 = aoff0 + (size_t)64 * lda;
    const size_t boff0 = (size_t)(n0 + srow) * ldb + cc8;
    const size_t boff1 = boff0 + (size_t)64 * ldb;

#define G_LOAD(k0) { \
    rah0 = *(const uint4*)(Ah + aoff0 + (k0)); rah1 = *(const uint4*)(Ah + aoff1 + (k0)); \
    ral0 = *(const uint4*)(Al + aoff0 + (k0)); ral1 = *(const uint4*)(Al + aoff1 + (k0)); \
    rbh0 = *(const uint4*)(Bh + boff0 + (k0)); rbh1 = *(const uint4*)(Bh + boff1 + (k0)); \
    rbl0 = *(const uint4*)(Bl + boff0 + (k0)); rbl1 = *(const uint4*)(Bl + boff1 + (k0)); }
#define G_STORE(b) { \
    st8(&Ash[b][0][srow][cc8], rah0); st8(&Ash[b][0][srow + 64][cc8], rah1); \
    st8(&Ash[b][1][srow][cc8], ral0); st8(&Ash[b][1][srow + 64][cc8], ral1); \
    st8(&Bsh[b][0][srow][cc8], rbh0); st8(&Bsh[b][0][srow + 64][cc8], rbh1); \
    st8(&Bsh[b][1][srow][cc8], rbl0); st8(&Bsh[b][1][srow + 64][cc8], rbl1); }

    const int nk = K >> 5;
    G_LOAD(0);
    G_STORE(0);
    __syncthreads();
    int cur = 0;
    for (int ik = 0; ik < nk; ++ik) {
        if (ik + 1 < nk) G_LOAD((ik + 1) << 5);
        bf16x8 bh[4], bl[4];
#pragma unroll
        for (int n = 0; n < 4; ++n) {
            bh[n] = ld16(&Bsh[cur][0][wc * 64 + n * 16 + fr][fg8]);
            bl[n] = ld16(&Bsh[cur][1][wc * 64 + n * 16 + fr][fg8]);
        }
#pragma unroll
        for (int m = 0; m < 4; ++m) {
            bf16x8 ah = ld16(&Ash[cur][0][wr * 64 + m * 16 + fr][fg8]);
            bf16x8 al = ld16(&Ash[cur][1][wr * 64 + m * 16 + fr][fg8]);
#pragma unroll
            for (int n = 0; n < 4; ++n) {
                acc[m][n] = __builtin_amdgcn_mfma_f32_16x16x32_bf16(ah, bh[n], acc[m][n], 0, 0, 0);
                acc[m][n] = __builtin_amdgcn_mfma_f32_16x16x32_bf16(ah, bl[n], acc[m][n], 0, 0, 0);
                acc[m][n] = __builtin_amdgcn_mfma_f32_16x16x32_bf16(al, bh[n], acc[m][n], 0, 0, 0);
            }
        }
        if (ik + 1 < nk) G_STORE(cur ^ 1);
        __syncthreads();
        cur ^= 1;
    }
    const long co = (long)(z >> cDiv) * cZ;
#pragma unroll
    for (int m = 0; m < 4; ++m) {
        int row_b = m0 + wr * 64 + m * 16 + (fg8 >> 1);
#pragma unroll
        for (int n = 0; n < 4; ++n) {
            int col = n0 + wc * 64 + n * 16 + fr;
#pragma unroll
            for (int j = 0; j < 4; ++j)
                C[co + (long)(row_b + j) * ldc + col] = alpha * acc[m][n][j];
        }
    }
#undef G_LOAD
#undef G_STORE
}

// ---------------- int-bf16 MFMA GEMM: C[m,n] = sa[m]*sb[n]*sum A*B^T -------
__global__ __launch_bounds__(256) void gemm_int_kernel(
    const u16* __restrict__ A, int lda, const float* __restrict__ sa,
    const u16* __restrict__ B, int ldb, const float* __restrict__ sb,
    float* __restrict__ C, int ldc, int K) {
    const int m0 = blockIdx.y * 128, n0 = blockIdx.x * 128;
    __shared__ u16 Ash[2][128][36];
    __shared__ u16 Bsh[2][128][36];
    const int tid = threadIdx.x, lane = tid & 63, wave = tid >> 6;
    const int wr = wave >> 1, wc = wave & 1;
    const int fr = lane & 15, fg8 = (lane >> 4) * 8;
    const int srow = tid >> 2, cc8 = (tid & 3) * 8;
    f32x4 acc[4][4];
#pragma unroll
    for (int m = 0; m < 4; ++m)
#pragma unroll
        for (int n = 0; n < 4; ++n) acc[m][n] = (f32x4)0.0f;

    uint4 ra0, ra1, rb0, rb1;
    const size_t aoff0 = (size_t)(m0 + srow) * lda + cc8;
    const size_t aoff1 = aoff0 + (size_t)64 * lda;
    const size_t boff0 = (size_t)(n0 + srow) * ldb + cc8;
    const size_t boff1 = boff0 + (size_t)64 * ldb;
#define GI_LOAD(k0) { \
    ra0 = *(const uint4*)(A + aoff0 + (k0)); ra1 = *(const uint4*)(A + aoff1 + (k0)); \
    rb0 = *(const uint4*)(B + boff0 + (k0)); rb1 = *(const uint4*)(B + boff1 + (k0)); }
#define GI_STORE(b) { \
    st8(&Ash[b][srow][cc8], ra0); st8(&Ash[b][srow + 64][cc8], ra1); \
    st8(&Bsh[b][srow][cc8], rb0); st8(&Bsh[b][srow + 64][cc8], rb1); }
    const int nk = K >> 5;
    GI_LOAD(0);
    GI_STORE(0);
    __syncthreads();
    int cur = 0;
    for (int ik = 0; ik < nk; ++ik) {
        if (ik + 1 < nk) GI_LOAD((ik + 1) << 5);
        bf16x8 bfr[4];
#pragma unroll
        for (int n = 0; n < 4; ++n)
            bfr[n] = ld16(&Bsh[cur][wc * 64 + n * 16 + fr][fg8]);
#pragma unroll
        for (int m = 0; m < 4; ++m) {
            bf16x8 ah = ld16(&Ash[cur][wr * 64 + m * 16 + fr][fg8]);
#pragma unroll
            for (int n = 0; n < 4; ++n)
                acc[m][n] = __builtin_amdgcn_mfma_f32_16x16x32_bf16(ah, bfr[n], acc[m][n], 0, 0, 0);
        }
        if (ik + 1 < nk) GI_STORE(cur ^ 1);
        __syncthreads();
        cur ^= 1;
    }
#pragma unroll
    for (int m = 0; m < 4; ++m) {
        int row_b = m0 + wr * 64 + m * 16 + (fg8 >> 1);
#pragma unroll
        for (int n = 0; n < 4; ++n) {
            int col = n0 + wc * 64 + n * 16 + fr;
            float sc = sb[col];
#pragma unroll
            for (int j = 0; j < 4; ++j)
                C[(long)(row_b + j) * ldc + col] = acc[m][n][j] * sa[row_b + j] * sc;
        }
    }
#undef GI_LOAD
#undef GI_STORE
}

// ---------------- per-row fake_quant -> int-valued bf16 + scale ------------
__global__ void rowquant_int_kernel(const float* __restrict__ x, u16* __restrict__ qi,
                                    float* __restrict__ sc, int cols) {
    __shared__ float red[256];
    int row = blockIdx.x, tid = threadIdx.x;
    const float* p = x + (size_t)row * cols;
    u16* q = qi + (size_t)row * cols;
    float m = 0.0f;
    for (int j = tid; j < cols; j += 256) m = fmaxf(m, fabsf(p[j]));
    red[tid] = m; __syncthreads();
    for (int s = 128; s > 0; s >>= 1) {
        if (tid < s) red[tid] = fmaxf(red[tid], red[tid + s]);
        __syncthreads();
    }
    float scale = fmaxf(red[0] / 127.0f, 1e-8f);
    if (tid == 0) sc[row] = scale;
    for (int j = tid; j < cols; j += 256) {
        float v = rintf(p[j] / scale);
        v = fminf(fmaxf(v, -127.0f), 127.0f);
        q[j] = f2bf(v);
    }
}

// ---------------- RoPE in place, x:(S, nh, 128), cos/sin:(S,128) -----------
__global__ void rope_kernel(float* __restrict__ x, const float* __restrict__ c,
                            const float* __restrict__ s, int nh) {
    int idx = blockIdx.x * 256 + threadIdx.x;
    int d = idx & 63;
    int t = idx >> 6;
    int h = t % nh;
    int sq = t / nh;
    size_t base = ((size_t)sq * nh + h) * 128;
    float a = x[base + d], b = x[base + d + 64];
    float c1 = c[sq * 128 + d], s1 = s[sq * 128 + d];
    float c2 = c[sq * 128 + d + 64], s2 = s[sq * 128 + d + 64];
    x[base + d] = a * c1 - b * s1;
    x[base + d + 64] = b * c2 + a * s2;
}

// ---------------- flash attention v3: swapped QK, KVBLK=32, split-K2 -------
// grid (16 heads, 32 q-tiles, 2 kv-parts). 256 thr = 4 waves, wave: 16 rows.
// Writes UNNORMALIZED o (per part) + m (log2 domain) + l.
__global__ __launch_bounds__(256, 4) void flash_kernel(
    const float* __restrict__ q2f,
    const u16* __restrict__ k2i, const float* __restrict__ ksc,
    const u16* __restrict__ vTi, const float* __restrict__ vsc,
    float* __restrict__ obuf, float* __restrict__ mlbuf) {
    const int h = blockIdx.x, qt = 31 - blockIdx.y, part = blockIdx.z, g = h >> 1;
    __shared__ u16 Ksh[2][32 * 128];
    __shared__ u16 Vsh[2][128 * 32];
    __shared__ u16 Psh[4][16 * 32];
    __shared__ float Kss[2][32];
    __shared__ float Vss[2][32];

    const int tid = threadIdx.x, lane = tid & 63, w = tid >> 6;
    const int lc = lane & 15, lg = lane >> 4;
    const float scale = 0.08838834764831845f;
    const float LOG2E = 1.4426950408889634f;
    const float THR = 10.0f;

    // Q fragments (scale folded), 2-plane split in registers (B operand)
    bf16x8 qh[4], ql[4];
    {
        int s = qt * 64 + w * 16 + lc;
        const float* qp = q2f + (size_t)s * 2048 + h * 128 + lg * 8;
#pragma unroll
        for (int kk = 0; kk < 4; ++kk) {
            float4 v0 = *(const float4*)(qp + kk * 32);
            float4 v1 = *(const float4*)(qp + kk * 32 + 4);
            float vv[8] = {v0.x, v0.y, v0.z, v0.w, v1.x, v1.y, v1.z, v1.w};
#pragma unroll
            for (int e = 0; e < 8; ++e) {
                float x = vv[e] * scale;
                u16 hh = f2bf(x);
                qh[kk][e] = (short)hh;
                ql[kk][e] = (short)f2bf(x - bf2f(hh));
            }
        }
    }

    f32x4 acc_o[8];
#pragma unroll
    for (int nn = 0; nn < 8; ++nn) acc_o[nn] = (f32x4)0.0f;
    float mj = -1e30f, lj = 0.0f;

    const int tn = qt + 1;          // tiles per part
    const int t0 = part * tn;       // global tile offset

    uint4 kreg0, kreg1, vreg0, vreg1; float sreg = 0.0f;
    const int sr = tid >> 4, sc4 = tid & 15;   // K stage coords
    const int sd = tid >> 2, svc = tid & 3;    // V stage coords

#define STAGE_LOAD(tg) { \
    const int j0_ = (tg) * 32; \
    kreg0 = *(const uint4*)(k2i + (size_t)(j0_ + sr) * 1024 + g * 128 + sc4 * 8); \
    kreg1 = *(const uint4*)(k2i + (size_t)(j0_ + sr + 16) * 1024 + g * 128 + sc4 * 8); \
    vreg0 = *(const uint4*)(vTi + (size_t)(g * 128 + sd) * 2048 + j0_ + svc * 8); \
    vreg1 = *(const uint4*)(vTi + (size_t)(g * 128 + sd + 64) * 2048 + j0_ + svc * 8); \
    if (tid < 32) sreg = ksc[(j0_ + tid) * 8 + g] * LOG2E; \
    else if (tid < 64) sreg = vsc[(j0_ + tid - 32) * 8 + g]; }

#define STAGE_WRITE(b) { \
    *(uint4*)(&Ksh[b][sr * 128 + ((sc4 ^ (sr & 7)) << 3)]) = kreg0; \
    *(uint4*)(&Ksh[b][(sr + 16) * 128 + ((sc4 ^ (sr & 7)) << 3)]) = kreg1; \
    *(uint4*)(&Vsh[b][sd * 32 + ((svc ^ (sd & 3)) << 3)]) = vreg0; \
    *(uint4*)(&Vsh[b][(sd + 64) * 32 + ((svc ^ (sd & 3)) << 3)]) = vreg1; \
    if (tid < 32) Kss[b][tid] = sreg; \
    else if (tid < 64) Vss[b][tid - 32] = sreg; }

    STAGE_LOAD(t0);
    STAGE_WRITE(0);
    __syncthreads();
    for (int t = 0; t < tn; ++t) {
        const int cur = t & 1;
        const int tg = t0 + t;
        if (t + 1 < tn) STAGE_LOAD(t0 + t + 1);

        // ---- QK^T swapped: D[k][q], q = lc ----
        f32x4 accs[2];
        accs[0] = (f32x4)0.0f; accs[1] = (f32x4)0.0f;
#pragma unroll
        for (int n = 0; n < 2; ++n) {
#pragma unroll
            for (int kk = 0; kk < 4; ++kk) {
                bf16x8 kf = ld16(&Ksh[cur][(n * 16 + lc) * 128 + (((kk * 4 + lg) ^ (lc & 7)) << 3)]);
                accs[n] = __builtin_amdgcn_mfma_f32_16x16x32_bf16(kf, qh[kk], accs[n], 0, 0, 0);
                accs[n] = __builtin_amdgcn_mfma_f32_16x16x32_bf16(kf, ql[kk], accs[n], 0, 0, 0);
            }
        }
        // column scale -> log2 domain (row of D = k-index)
#pragma unroll
        for (int n = 0; n < 2; ++n)
#pragma unroll
            for (int j = 0; j < 4; ++j)
                accs[n][j] *= Kss[cur][n * 16 + lg * 4 + j];
        // causal mask (only near-diagonal tiles)
        if (tg >= 2 * qt) {
            int qg = qt * 64 + w * 16 + lc;
#pragma unroll
            for (int n = 0; n < 2; ++n)
#pragma unroll
                for (int j = 0; j < 4; ++j) {
                    int kg = tg * 32 + n * 16 + lg * 4 + j;
                    if (kg > qg) accs[n][j] = -3.0e38f;
                }
        }

        // ---- row stats: in-register + 2 shuffles ----
        float pm = accs[0][0];
#pragma unroll
        for (int j = 1; j < 4; ++j) pm = fmaxf(pm, accs[0][j]);
#pragma unroll
        for (int j = 0; j < 4; ++j) pm = fmaxf(pm, accs[1][j]);
        pm = fmaxf(pm, __shfl_xor(pm, 16));
        pm = fmaxf(pm, __shfl_xor(pm, 32));
        bool need = pm > mj + THR;
        float mn = need ? pm : mj;
        float sf = need ? exp2f(mj - mn) : 1.0f;
        mj = mn;
        if (__any(need)) {
            float sfj[4];
#pragma unroll
            for (int j = 0; j < 4; ++j) sfj[j] = __shfl(sf, lg * 4 + j);
#pragma unroll
            for (int nn = 0; nn < 8; ++nn)
#pragma unroll
                for (int j = 0; j < 4; ++j) acc_o[nn][j] *= sfj[j];
        }
        float rowsum = 0.0f;
#pragma unroll
        for (int n = 0; n < 2; ++n)
#pragma unroll
            for (int j = 0; j < 4; ++j) {
                float p = exp2f(accs[n][j] - mj);
                accs[n][j] = p;
                rowsum += p;
            }
        rowsum += __shfl_xor(rowsum, 16);
        rowsum += __shfl_xor(rowsum, 32);
        lj = lj * sf + rowsum;

        // ---- P' = P * vscale(k) -> wave-private LDS, then A-frag read ----
#pragma unroll
        for (int n = 0; n < 2; ++n)
#pragma unroll
            for (int j = 0; j < 4; ++j) {
                int k = n * 16 + lg * 4 + j;
                u16 val = f2bf(accs[n][j] * Vss[cur][k]);
                Psh[w][lc * 32 + (((k >> 3) ^ (lc & 3)) << 3) + (k & 7)] = val;
            }
        bf16x8 pf = ld16(&Psh[w][lc * 32 + ((lg ^ (lc & 3)) << 3)]);

        // ---- PV ----
#pragma unroll
        for (int nn = 0; nn < 8; ++nn) {
            bf16x8 vf = ld16(&Vsh[cur][(nn * 16 + lc) * 32 + ((lg ^ (lc & 3)) << 3)]);
            acc_o[nn] = __builtin_amdgcn_mfma_f32_16x16x32_bf16(pf, vf, acc_o[nn], 0, 0, 0);
        }
        if (t + 1 < tn) STAGE_WRITE(cur ^ 1);
        __syncthreads();
    }
#undef STAGE_LOAD
#undef STAGE_WRITE

    // ---- epilogue: unnormalized o + (m, l) ----
    float* op = obuf + (size_t)part * 4194304 + ((size_t)h * 2048 + qt * 64 + w * 16) * 128;
#pragma unroll
    for (int nn = 0; nn < 8; ++nn)
#pragma unroll
        for (int j = 0; j < 4; ++j)
            op[(lg * 4 + j) * 128 + nn * 16 + lc] = acc_o[nn][j];
    if (lg == 0) {
        int rs = h * 2048 + qt * 64 + w * 16 + lc;
        mlbuf[part * 65536 + rs] = mj;
        mlbuf[part * 65536 + 32768 + rs] = lj;
    }
}

// ---------------- split-K combine ------------------------------------------
__global__ void combine_kernel(const float* __restrict__ o01,
                               const float* __restrict__ ml,
                               float* __restrict__ of) {
    int idx = blockIdx.x * 256 + threadIdx.x;
    int hs = idx >> 7;
    float m0 = ml[hs], l0 = ml[32768 + hs];
    float m1 = ml[65536 + hs], l1 = ml[98304 + hs];
    float m = fmaxf(m0, m1);
    float w0 = exp2f(m0 - m), w1 = exp2f(m1 - m);
    float l = l0 * w0 + l1 * w1;
    of[idx] = (o01[idx] * w0 + o01[4194304 + idx] * w1) / l;
}

// ===========================================================================
extern "C" void kernel_launch(void* const* d_in, const int* in_sizes, int n_in,
                              void* d_out, int out_size, void* d_ws, size_t ws_size,
                              hipStream_t stream) {
    const float* hidden = (const float*)d_in[0];
    const float* cosp   = (const float*)d_in[1];
    const float* sinp   = (const float*)d_in[2];
    const float* Wq     = (const float*)d_in[3];
    const float* Wk     = (const float*)d_in[4];
    const float* Wv     = (const float*)d_in[5];
    const float* Wo     = (const float*)d_in[6];
    const float* Lp     = (const float*)d_in[7];
    const float* Rp     = (const float*)d_in[8];
    const float* diag   = (const float*)d_in[9];
    const float* Tkp    = (const float*)d_in[10];
    const float* Tvp    = (const float*)d_in[11];
    float* out = (float*)d_out;

    const size_t MiB = 1ull << 20;
    char* W = (char*)d_ws;
    auto F = [&](size_t mb) { return (float*)(W + mb * MiB); };
    auto U = [&](size_t mb) { return (u16*)(W + mb * MiB); };
    const long HP = 4194304, HP2 = 2097152;

    // small scratch in d_out (final GEMM overwrites all of d_out)
    float* dsc   = (float*)d_out;
    float* invL  = dsc;
    float* invR  = dsc + 1024;
    float* invTk = dsc + 5120;
    float* invTv = dsc + 21504;
    u16* sm = (u16*)(dsc + 37888);
    u16* invTk_sh = sm;              u16* invTk_sl = sm + 16384;
    u16* TkT_sh   = sm + 2 * 16384;  u16* TkT_sl   = sm + 3 * 16384;
    u16* invTvT_sh= sm + 4 * 16384;  u16* invTvT_sl= sm + 5 * 16384;
    u16* TvT_sh   = sm + 6 * 16384;  u16* TvT_sl   = sm + 7 * 16384;

    auto gemm = [&](dim3 grid,
                    const u16* Ah, const u16* Al, int lda, long aZ, int aDiv,
                    const u16* Bh, const u16* Bl, int ldb, long bZ, int bDiv,
                    float* C, int ldc, long cZ, int cDiv, int K, float alpha) {
        gemm_kernel<<<grid, 256, 0, stream>>>(Ah, Al, lda, aZ, aDiv,
            Bh, Bl, ldb, bZ, bDiv, C, ldc, cZ, cDiv, K, alpha);
    };

    // scales area: F(88)
    float* xs  = F(88);
    float* wqs = xs + 2048;
    float* wks = wqs + 2048;
    float* wvs = wks + 1024;
    float* k2s = wvs + 1024;        // 16384
    float* vs  = k2s + 16384;       // 16384
    float* o2s = vs + 16384;
    float* wos = o2s + 2048;

    // ---- P0: inverses + small splits ----
    gj4_kernel<<<4, 1024, 0, stream>>>(Lp, invL, Rp, invR, Tkp, invTk, Tvp, invTv);
    split_kernel<<<16, 256, 0, stream>>>(invTk, invTk_sh, invTk_sl, 16384);
    split_t_kernel<<<dim3(4, 4), 256, 0, stream>>>(Tkp, TkT_sh, TkT_sl, 128, 128);
    split_t_kernel<<<dim3(4, 4), 256, 0, stream>>>(invTv, invTvT_sh, invTvT_sl, 128, 128);
    split_t_kernel<<<dim3(4, 4), 256, 0, stream>>>(Tvp, TvT_sh, TvT_sl, 128, 128);

    u16* PT_s   = U(0);    // [0,16)
    u16* PINV_s = U(16);   // [16,32)
    build_PT_s_kernel<<<16384, 256, 0, stream>>>(Lp, Rp, diag, PT_s, PT_s + HP);
    build_Pinv_s_kernel<<<16384, 256, 0, stream>>>(invL, invR, diag, PINV_s, PINV_s + HP);

    // ---- P1: weight prep -> int-bf16 + scales ----
    u16* tmp_s = U(32);   // [32,48)
    float* tmpf = F(48);  // [48,64)
    u16* WQi = U(64);     // [64,72)
    u16* WKi = U(72);     // [72,76)
    u16* WVi = U(76);     // [76,80)
    u16* Xi  = U(80);     // [80,88)

    split_kernel<<<4096, 256, 0, stream>>>(Wq, tmp_s, tmp_s + HP, 4194304);
    gemm(dim3(16, 16, 1), tmp_s, tmp_s + HP, 2048, 0, 0,
         PINV_s, PINV_s + HP, 2048, 0, 0, tmpf, 2048, 0, 0, 2048, 1.0f);
    rowquant_int_kernel<<<2048, 256, 0, stream>>>(tmpf, WQi, wqs, 2048);

    split_kernel<<<2048, 256, 0, stream>>>(Wk, tmp_s, tmp_s + HP2, 2097152);
    gemm(dim3(16, 8, 1), tmp_s, tmp_s + HP2, 2048, 0, 0,
         PINV_s, PINV_s + HP, 2048, 0, 0, tmpf, 2048, 0, 0, 2048, 1.0f);
    rowquant_int_kernel<<<1024, 256, 0, stream>>>(tmpf, WKi, wks, 2048);

    split_kernel<<<2048, 256, 0, stream>>>(Wv, tmp_s, tmp_s + HP2, 2097152);
    gemm(dim3(16, 8, 1), tmp_s, tmp_s + HP2, 2048, 0, 0,
         PINV_s, PINV_s + HP, 2048, 0, 0, tmpf, 2048, 0, 0, 2048, 1.0f);
    u16* WVPt_s = U(56);  // [56,64)
    split_t_kernel<<<dim3(64, 32), 256, 0, stream>>>(tmpf, WVPt_s, WVPt_s + HP2, 1024, 2048);
    float* WVf = F(40);   // [40,48)
    gemm(dim3(16, 1, 8), TvT_sh, TvT_sl, 128, 0, 0,
         WVPt_s, WVPt_s + HP2, 1024, 128, 0, WVf, 2048, (long)128 * 2048, 0, 128, 1.0f);
    rowquant_int_kernel<<<1024, 256, 0, stream>>>(WVf, WVi, wvs, 2048);

    split_kernel<<<4096, 256, 0, stream>>>(hidden, tmp_s, tmp_s + HP, 4194304);
    gemm(dim3(16, 16, 1), tmp_s, tmp_s + HP, 2048, 0, 0,
         PT_s, PT_s + HP, 2048, 0, 0, tmpf, 2048, 0, 0, 2048, 1.0f);
    rowquant_int_kernel<<<2048, 256, 0, stream>>>(tmpf, Xi, xs, 2048);

    // ---- P2: projections (exact int GEMMs), RoPE, head transforms ----
    float* Qf  = F(0);    // [0,16) over PT_s (dead)
    float* KBf = F(16);   // [16,24) over PINV_s (dead)
    float* Vf  = F(24);   // [24,32)
    gemm_int_kernel<<<dim3(16, 16), 256, 0, stream>>>(Xi, 2048, xs, WQi, 2048, wqs, Qf, 2048, 2048);
    gemm_int_kernel<<<dim3(8, 16), 256, 0, stream>>>(Xi, 2048, xs, WKi, 2048, wks, KBf, 1024, 2048);
    gemm_int_kernel<<<dim3(8, 16), 256, 0, stream>>>(Xi, 2048, xs, WVi, 2048, wvs, Vf, 1024, 2048);

    rope_kernel<<<8192, 256, 0, stream>>>(Qf, cosp, sinp, 16);
    rope_kernel<<<4096, 256, 0, stream>>>(KBf, cosp, sinp, 8);

    // K path: k2 = fake_quant(k @ Tk) -> int + scale
    u16* KB_s = U(32);    // [32,40) over tmp_s (dead)
    split_kernel<<<2048, 256, 0, stream>>>(KBf, KB_s, KB_s + HP2, 2097152);
    float* k2f = F(40);   // [40,48) over WVf (dead)
    gemm(dim3(1, 16, 8), KB_s, KB_s + HP2, 1024, 128, 0,
         TkT_sh, TkT_sl, 128, 0, 0, k2f, 1024, 128, 0, 128, 1.0f);
    u16* k2i = U(64);     // [64,68) over WQi (dead)
    rowquant_int_kernel<<<16384, 256, 0, stream>>>(k2f, k2i, k2s, 128);

    // V path: fake_quant(v) -> int + scale, then transpose
    u16* Vi = U(68);      // [68,72)
    rowquant_int_kernel<<<16384, 256, 0, stream>>>(Vf, Vi, vs, 128);
    u16* vTi = U(72);     // [72,76) over WKi (dead)
    trans16_kernel<<<dim3(16, 32), 256, 0, stream>>>(Vi, vTi, 2048, 1024);

    // Q path: q2 = q @ inv(Tk)^T
    u16* Q_s = U(16);     // [16,32) over KBf/Vf (dead)
    split_kernel<<<4096, 256, 0, stream>>>(Qf, Q_s, Q_s + HP, 4194304);
    float* q2f = F(32);   // [32,48) over KB_s/k2f (dead)
    gemm(dim3(1, 16, 16), Q_s, Q_s + HP, 2048, 128, 0,
         invTk_sh, invTk_sl, 128, 0, 0, q2f, 2048, 128, 0, 128, 1.0f);

    // ---- P3: flash attention (split-K 2) + combine ----
    float* o01 = F(0);    // o0 [0,16) over Qf (dead); o1 [16,32) over Q_s (dead)
    float* ml  = F(48);   // [48,48.5) over tmpf (dead)
    flash_kernel<<<dim3(16, 32, 2), 256, 0, stream>>>(q2f, k2i, k2s, vTi, vs, o01, ml);
    float* of = F(56);    // [56,72) over WVPt/k2i/Vi (dead after flash)
    combine_kernel<<<16384, 256, 0, stream>>>(o01, ml, of);

    // ---- P4: output transform + final projection ----
    u16* o_s = U(0);      // [0,16) over o0 (dead after combine)
    split_kernel<<<4096, 256, 0, stream>>>(of, o_s, o_s + HP, 4194304);
    float* o2f = F(16);   // [16,32) over o1 (dead)
    gemm(dim3(1, 16, 16), o_s, o_s + HP, 128, 262144, 0,
         invTvT_sh, invTvT_sl, 128, 0, 0, o2f, 2048, 128, 0, 128, 1.0f);
    u16* o2i = U(32);     // [32,40)
    rowquant_int_kernel<<<2048, 256, 0, stream>>>(o2f, o2i, o2s, 2048);
    u16* Woi = U(40);     // [40,48)
    rowquant_int_kernel<<<2048, 256, 0, stream>>>(Wo, Woi, wos, 2048);
    gemm_int_kernel<<<dim3(16, 16), 256, 0, stream>>>(o2i, 2048, o2s, Woi, 2048, wos, out, 2048, 2048);

    (void)in_sizes; (void)n_in; (void)out_size; (void)ws_size;
}